// Round 1
// baseline (2471.982 us; speedup 1.0000x reference)
//
#include <hip/hip_runtime.h>
#include <math.h>

#define DM   1024   // d_model
#define DI   2048   // d_inner
#define DTR  64     // dt_rank
#define DST  16     // d_state
#define NB   2      // batch
#define LL   1024   // seq len
#define MR   (NB*LL)  // 2048 rows

__device__ __forceinline__ float siluf(float x) { return x / (1.f + __expf(-x)); }
__device__ __forceinline__ float softplusf(float x) {
    return fmaxf(x, 0.f) + log1pf(__expf(-fabsf(x)));
}

// ---------------- LayerNorm: one block per row of 1024 ----------------
__global__ __launch_bounds__(256) void layernorm_k(
    const float* __restrict__ x, const float* __restrict__ w,
    const float* __restrict__ b, float* __restrict__ out)
{
    int row = blockIdx.x;
    int tid = threadIdx.x;
    const float* xr = x + (size_t)row * DM;
    float4 v = *(const float4*)(xr + tid * 4);
    float s = v.x + v.y + v.z + v.w;
    float q = v.x*v.x + v.y*v.y + v.z*v.z + v.w*v.w;
    #pragma unroll
    for (int off = 32; off > 0; off >>= 1) {
        s += __shfl_xor(s, off, 64);
        q += __shfl_xor(q, off, 64);
    }
    __shared__ float ss[4], qq[4];
    int wv = tid >> 6;
    if ((tid & 63) == 0) { ss[wv] = s; qq[wv] = q; }
    __syncthreads();
    s = ss[0] + ss[1] + ss[2] + ss[3];
    q = qq[0] + qq[1] + qq[2] + qq[3];
    float mu  = s * (1.f / DM);
    float var = q * (1.f / DM) - mu * mu;
    float rstd = rsqrtf(var + 1e-5f);
    float4 wv4 = *(const float4*)(w + tid * 4);
    float4 bv4 = *(const float4*)(b + tid * 4);
    float4 o;
    o.x = (v.x - mu) * rstd * wv4.x + bv4.x;
    o.y = (v.y - mu) * rstd * wv4.y + bv4.y;
    o.z = (v.z - mu) * rstd * wv4.z + bv4.z;
    o.w = (v.w - mu) * rstd * wv4.w + bv4.w;
    *(float4*)(out + (size_t)row * DM + tid * 4) = o;
}

// ---------------- Generic fp32 GEMM: C[m,n] = sum_k A[m,k]*B[n,k] ----------------
// EPI: 0 = none, 1 = softplus(acc + bias[n]), 2 = acc + bias[n] + res[m,n]
// M must be multiple of 64 (true for all calls: M=2048); K multiple of 16; N ragged ok.
template<int EPI>
__device__ __forceinline__ float epi_apply(float t, int row, int col,
                                           const float* bias, const float* res, int ldres)
{
    if (EPI == 1) t = softplusf(t + bias[col]);
    else if (EPI == 2) t = t + bias[col] + res[(size_t)row * ldres + col];
    return t;
}

template<int EPI>
__global__ __launch_bounds__(256) void gemm_abt(
    const float* __restrict__ A, int lda,
    const float* __restrict__ B, int ldb,
    float* __restrict__ C, int ldc,
    int N, int K,
    const float* __restrict__ bias,
    const float* __restrict__ res, int ldres)
{
    __shared__ float As[16][68];   // [k][m], row stride 68 floats (16B-aligned, conflict-light)
    __shared__ float Bs[16][68];   // [k][n]
    const int tid = threadIdx.x;
    const int bm = blockIdx.y * 64;
    const int bn = blockIdx.x * 64;
    const int lr = tid >> 2;          // 0..63 row within tile
    const int lk = (tid & 3) << 2;    // 0,4,8,12 k within tile
    const int tx = tid & 15;          // micro-tile col group
    const int ty = tid >> 4;          // micro-tile row group
    float acc[4][4] = {};

    for (int k0 = 0; k0 < K; k0 += 16) {
        float4 av = *(const float4*)(A + (size_t)(bm + lr) * lda + (k0 + lk));
        float4 bv = make_float4(0.f, 0.f, 0.f, 0.f);
        if (bn + lr < N)
            bv = *(const float4*)(B + (size_t)(bn + lr) * ldb + (k0 + lk));
        As[lk+0][lr] = av.x; As[lk+1][lr] = av.y; As[lk+2][lr] = av.z; As[lk+3][lr] = av.w;
        Bs[lk+0][lr] = bv.x; Bs[lk+1][lr] = bv.y; Bs[lk+2][lr] = bv.z; Bs[lk+3][lr] = bv.w;
        __syncthreads();
        #pragma unroll
        for (int kk = 0; kk < 16; ++kk) {
            float4 a4 = *(const float4*)&As[kk][ty << 2];
            float4 b4 = *(const float4*)&Bs[kk][tx << 2];
            float a[4] = {a4.x, a4.y, a4.z, a4.w};
            float b[4] = {b4.x, b4.y, b4.z, b4.w};
            #pragma unroll
            for (int i = 0; i < 4; ++i)
                #pragma unroll
                for (int j = 0; j < 4; ++j)
                    acc[i][j] = fmaf(a[i], b[j], acc[i][j]);
        }
        __syncthreads();
    }

    #pragma unroll
    for (int i = 0; i < 4; ++i) {
        int row  = bm + (ty << 2) + i;
        int col0 = bn + (tx << 2);
        if (col0 + 3 < N) {
            float4 o;
            o.x = epi_apply<EPI>(acc[i][0], row, col0+0, bias, res, ldres);
            o.y = epi_apply<EPI>(acc[i][1], row, col0+1, bias, res, ldres);
            o.z = epi_apply<EPI>(acc[i][2], row, col0+2, bias, res, ldres);
            o.w = epi_apply<EPI>(acc[i][3], row, col0+3, bias, res, ldres);
            *(float4*)(C + (size_t)row * ldc + col0) = o;
        } else {
            #pragma unroll
            for (int j = 0; j < 4; ++j) {
                int col = col0 + j;
                if (col < N)
                    C[(size_t)row * ldc + col] =
                        epi_apply<EPI>(acc[i][j], row, col, bias, res, ldres);
            }
        }
    }
}

// ---------------- Depthwise causal/anticausal conv (width 4) + SiLU ----------------
// xz: [MR, 2*DI]; xs source = first DI columns. Output xs: [MR, DI].
// dir==0: out[t] = w0*x[t-3]+w1*x[t-2]+w2*x[t-1]+w3*x[t]   (zero pad at batch start)
// dir==1: out[t] = w0*x[t+3]+w1*x[t+2]+w2*x[t+1]+w3*x[t]   (zero pad at batch end)
__global__ __launch_bounds__(256) void conv_silu_k(
    const float* __restrict__ xz, const float* __restrict__ convW,
    const float* __restrict__ convb, float* __restrict__ xs, int dir)
{
    int idx = blockIdx.x * 256 + threadIdx.x;   // over MR*DI
    int d = idx & (DI - 1);
    int m = idx >> 11;                          // DI == 2048
    int t = m & (LL - 1);
    int bb = m >> 10;                           // LL == 1024
    const float* w = convW + d * 4;
    float acc = convb[d];
    if (dir == 0) {
        #pragma unroll
        for (int k = 0; k < 4; ++k) {
            int tt = t - 3 + k;
            if (tt >= 0)
                acc = fmaf(w[k], xz[(size_t)(bb * LL + tt) * (2 * DI) + d], acc);
        }
    } else {
        #pragma unroll
        for (int k = 0; k < 4; ++k) {
            int tt = t + 3 - k;
            if (tt < LL)
                acc = fmaf(w[k], xz[(size_t)(bb * LL + tt) * (2 * DI) + d], acc);
        }
    }
    xs[(size_t)m * DI + d] = siluf(acc);
}

// ---------------- Selective scan, fused with (y + xs*D)*silu(z) epilogue ----------------
// One thread per channel d; h[16] in registers; grid (DI/256, NB).
__global__ __launch_bounds__(256) void scan_k(
    const float* __restrict__ dtf, const float* __restrict__ xs,
    const float* __restrict__ xdb, const float* __restrict__ xz,
    const float* __restrict__ A_log, const float* __restrict__ Dskip,
    float* __restrict__ y, int dir)
{
    int d  = blockIdx.x * 256 + threadIdx.x;  // 0..DI-1
    int bb = blockIdx.y;
    float Ad[DST];
    #pragma unroll
    for (int s = 0; s < DST; ++s) Ad[s] = -__expf(A_log[d * DST + s]);
    float Dsk = Dskip[d];
    float h[DST];
    #pragma unroll
    for (int s = 0; s < DST; ++s) h[s] = 0.f;

    for (int i = 0; i < LL; ++i) {
        int t = dir ? (LL - 1 - i) : i;
        size_t m = (size_t)bb * LL + t;
        float dtv = dtf[m * DI + d];
        float xv  = xs[m * DI + d];
        const float* bc = xdb + m * 96;      // [0:64]=dt_low, [64:80]=B, [80:96]=C
        float dtx = dtv * xv;
        float yv = 0.f;
        #pragma unroll
        for (int s = 0; s < DST; ++s) {
            float dA  = __expf(dtv * Ad[s]);
            float dBx = dtx * bc[64 + s];
            h[s] = fmaf(h[s], dA, dBx);
            yv = fmaf(h[s], bc[80 + s], yv);
        }
        float zv = xz[m * (2 * DI) + DI + d];
        y[m * DI + d] = (yv + xv * Dsk) * siluf(zv);
    }
}

// ---------------- Launch ----------------
extern "C" void kernel_launch(void* const* d_in, const int* in_sizes, int n_in,
                              void* d_out, int out_size, void* d_ws, size_t ws_size,
                              hipStream_t stream)
{
    const float* x      = (const float*)d_in[0];
    const float* ln_w   = (const float*)d_in[1];
    const float* ln_b   = (const float*)d_in[2];
    const float* proj_W = (const float*)d_in[21];
    const float* proj_b = (const float*)d_in[22];

    float* ws = (float*)d_ws;
    float* normed = ws;                                  // MR*DM
    float* xz     = normed + (size_t)MR * DM;            // MR*2*DI
    float* xs     = xz     + (size_t)MR * 2 * DI;        // MR*DI
    float* xdb    = xs     + (size_t)MR * DI;            // MR*96
    float* dtf    = xdb    + (size_t)MR * 96;            // MR*DI
    float* yb     = dtf    + (size_t)MR * DI;            // MR*DI
    float* comb   = yb     + (size_t)MR * DI;            // MR*2*DM

    layernorm_k<<<MR, 256, 0, stream>>>(x, ln_w, ln_b, normed);

    for (int dir = 0; dir < 2; ++dir) {
        const float* inW    = (const float*)d_in[3 + 9 * dir + 0];
        const float* convW  = (const float*)d_in[3 + 9 * dir + 1];
        const float* convb  = (const float*)d_in[3 + 9 * dir + 2];
        const float* xprojW = (const float*)d_in[3 + 9 * dir + 3];
        const float* dtW    = (const float*)d_in[3 + 9 * dir + 4];
        const float* dtb    = (const float*)d_in[3 + 9 * dir + 5];
        const float* A_log  = (const float*)d_in[3 + 9 * dir + 6];
        const float* Dskip  = (const float*)d_in[3 + 9 * dir + 7];
        const float* outW   = (const float*)d_in[3 + 9 * dir + 8];

        // xz = normed @ inW^T           [MR, 2*DI]
        gemm_abt<0><<<dim3((2 * DI) / 64, MR / 64), 256, 0, stream>>>(
            normed, DM, inW, DM, xz, 2 * DI, 2 * DI, DM, nullptr, nullptr, 0);

        // xs = silu(depthwise_conv(xz[:, :DI]))
        conv_silu_k<<<(MR * DI) / 256, 256, 0, stream>>>(xz, convW, convb, xs, dir);

        // xdb = xs @ xprojW^T           [MR, 96]
        gemm_abt<0><<<dim3((96 + 63) / 64, MR / 64), 256, 0, stream>>>(
            xs, DI, xprojW, DI, xdb, 96, 96, DI, nullptr, nullptr, 0);

        // dtf = softplus(xdb[:, :64] @ dtW^T + dtb)   [MR, DI]
        gemm_abt<1><<<dim3(DI / 64, MR / 64), 256, 0, stream>>>(
            xdb, 96, dtW, DTR, dtf, DI, DI, DTR, dtb, nullptr, 0);

        // fused selective scan + gating epilogue -> yb [MR, DI]
        scan_k<<<dim3(DI / 256, NB), 256, 0, stream>>>(
            dtf, xs, xdb, xz, A_log, Dskip, yb, dir);

        // out-proj into the concat buffer: comb[:, dir*DM : dir*DM+DM]
        gemm_abt<0><<<dim3(DM / 64, MR / 64), 256, 0, stream>>>(
            yb, DI, outW, DI, comb + dir * DM, 2 * DM, DM, DI, nullptr, nullptr, 0);
    }

    // final: out = x + comb @ proj_W^T + proj_b
    gemm_abt<2><<<dim3(DM / 64, MR / 64), 256, 0, stream>>>(
        comb, 2 * DM, proj_W, 2 * DM, (float*)d_out, DM, DM, 2 * DM, proj_b, x, DM);
}

// Round 2
// 1503.112 us; speedup vs baseline: 1.6446x; 1.6446x over previous
//
#include <hip/hip_runtime.h>
#include <math.h>

#define DM   1024   // d_model
#define DI   2048   // d_inner
#define DTR  64     // dt_rank
#define DST  16     // d_state
#define NB   2      // batch
#define LL   1024   // seq len
#define MR   (NB*LL)  // 2048 rows

__device__ __forceinline__ float siluf(float x) { return x / (1.f + __expf(-x)); }
__device__ __forceinline__ float softplusf(float x) {
    return fmaxf(x, 0.f) + log1pf(__expf(-fabsf(x)));
}

// ---------------- LayerNorm: one block per row of 1024 ----------------
__global__ __launch_bounds__(256) void layernorm_k(
    const float* __restrict__ x, const float* __restrict__ w,
    const float* __restrict__ b, float* __restrict__ out)
{
    int row = blockIdx.x;
    int tid = threadIdx.x;
    const float* xr = x + (size_t)row * DM;
    float4 v = *(const float4*)(xr + tid * 4);
    float s = v.x + v.y + v.z + v.w;
    float q = v.x*v.x + v.y*v.y + v.z*v.z + v.w*v.w;
    #pragma unroll
    for (int off = 32; off > 0; off >>= 1) {
        s += __shfl_xor(s, off, 64);
        q += __shfl_xor(q, off, 64);
    }
    __shared__ float ss[4], qq[4];
    int wv = tid >> 6;
    if ((tid & 63) == 0) { ss[wv] = s; qq[wv] = q; }
    __syncthreads();
    s = ss[0] + ss[1] + ss[2] + ss[3];
    q = qq[0] + qq[1] + qq[2] + qq[3];
    float mu  = s * (1.f / DM);
    float var = q * (1.f / DM) - mu * mu;
    float rstd = rsqrtf(var + 1e-5f);
    float4 wv4 = *(const float4*)(w + tid * 4);
    float4 bv4 = *(const float4*)(b + tid * 4);
    float4 o;
    o.x = (v.x - mu) * rstd * wv4.x + bv4.x;
    o.y = (v.y - mu) * rstd * wv4.y + bv4.y;
    o.z = (v.z - mu) * rstd * wv4.z + bv4.z;
    o.w = (v.w - mu) * rstd * wv4.w + bv4.w;
    *(float4*)(out + (size_t)row * DM + tid * 4) = o;
}

// ---------------- Generic fp32 GEMM: C[m,n] = sum_k A[m,k]*B[n,k] ----------------
template<int EPI>
__device__ __forceinline__ float epi_apply(float t, int row, int col,
                                           const float* bias, const float* res, int ldres)
{
    if (EPI == 1) t = softplusf(t + bias[col]);
    else if (EPI == 2) t = t + bias[col] + res[(size_t)row * ldres + col];
    return t;
}

template<int EPI>
__global__ __launch_bounds__(256) void gemm_abt(
    const float* __restrict__ A, int lda,
    const float* __restrict__ B, int ldb,
    float* __restrict__ C, int ldc,
    int N, int K,
    const float* __restrict__ bias,
    const float* __restrict__ res, int ldres)
{
    __shared__ float As[16][68];
    __shared__ float Bs[16][68];
    const int tid = threadIdx.x;
    const int bm = blockIdx.y * 64;
    const int bn = blockIdx.x * 64;
    const int lr = tid >> 2;
    const int lk = (tid & 3) << 2;
    const int tx = tid & 15;
    const int ty = tid >> 4;
    float acc[4][4] = {};

    for (int k0 = 0; k0 < K; k0 += 16) {
        float4 av = *(const float4*)(A + (size_t)(bm + lr) * lda + (k0 + lk));
        float4 bv = make_float4(0.f, 0.f, 0.f, 0.f);
        if (bn + lr < N)
            bv = *(const float4*)(B + (size_t)(bn + lr) * ldb + (k0 + lk));
        As[lk+0][lr] = av.x; As[lk+1][lr] = av.y; As[lk+2][lr] = av.z; As[lk+3][lr] = av.w;
        Bs[lk+0][lr] = bv.x; Bs[lk+1][lr] = bv.y; Bs[lk+2][lr] = bv.z; Bs[lk+3][lr] = bv.w;
        __syncthreads();
        #pragma unroll
        for (int kk = 0; kk < 16; ++kk) {
            float4 a4 = *(const float4*)&As[kk][ty << 2];
            float4 b4 = *(const float4*)&Bs[kk][tx << 2];
            float a[4] = {a4.x, a4.y, a4.z, a4.w};
            float b[4] = {b4.x, b4.y, b4.z, b4.w};
            #pragma unroll
            for (int i = 0; i < 4; ++i)
                #pragma unroll
                for (int j = 0; j < 4; ++j)
                    acc[i][j] = fmaf(a[i], b[j], acc[i][j]);
        }
        __syncthreads();
    }

    #pragma unroll
    for (int i = 0; i < 4; ++i) {
        int row  = bm + (ty << 2) + i;
        int col0 = bn + (tx << 2);
        if (col0 + 3 < N) {
            float4 o;
            o.x = epi_apply<EPI>(acc[i][0], row, col0+0, bias, res, ldres);
            o.y = epi_apply<EPI>(acc[i][1], row, col0+1, bias, res, ldres);
            o.z = epi_apply<EPI>(acc[i][2], row, col0+2, bias, res, ldres);
            o.w = epi_apply<EPI>(acc[i][3], row, col0+3, bias, res, ldres);
            *(float4*)(C + (size_t)row * ldc + col0) = o;
        } else {
            #pragma unroll
            for (int j = 0; j < 4; ++j) {
                int col = col0 + j;
                if (col < N)
                    C[(size_t)row * ldc + col] =
                        epi_apply<EPI>(acc[i][j], row, col, bias, res, ldres);
            }
        }
    }
}

// ---------------- Depthwise conv (width 4) + SiLU ----------------
__global__ __launch_bounds__(256) void conv_silu_k(
    const float* __restrict__ xz, const float* __restrict__ convW,
    const float* __restrict__ convb, float* __restrict__ xs, int dir)
{
    int idx = blockIdx.x * 256 + threadIdx.x;
    int d = idx & (DI - 1);
    int m = idx >> 11;
    int t = m & (LL - 1);
    int bb = m >> 10;
    const float* w = convW + d * 4;
    float acc = convb[d];
    if (dir == 0) {
        #pragma unroll
        for (int k = 0; k < 4; ++k) {
            int tt = t - 3 + k;
            if (tt >= 0)
                acc = fmaf(w[k], xz[(size_t)(bb * LL + tt) * (2 * DI) + d], acc);
        }
    } else {
        #pragma unroll
        for (int k = 0; k < 4; ++k) {
            int tt = t + 3 - k;
            if (tt < LL)
                acc = fmaf(w[k], xz[(size_t)(bb * LL + tt) * (2 * DI) + d], acc);
        }
    }
    xs[(size_t)m * DI + d] = siluf(acc);
}

// ---------------- Chunked selective scan ----------------
// Linear recurrence h_t = dA_t*h_{t-1} + dBx_t decomposes exactly over chunks:
//   pass1: per chunk, h_end (with h0=0) and Aprod = prod(dA) over chunk
//   pass2: sequential carry combine over G chunks (in-place hend -> h_in)
//   pass3: per chunk, rerun from true h_in, emit y + gating epilogue
// Buffers laid out [g][b][d][s].

__global__ __launch_bounds__(256) void scan1_k(
    const float* __restrict__ dtf, const float* __restrict__ xs,
    const float* __restrict__ xdb, const float* __restrict__ A_log,
    float* __restrict__ hend, float* __restrict__ aprod, int dir, int Cn)
{
    int d  = blockIdx.x * 256 + threadIdx.x;
    int bb = blockIdx.y;
    int g  = blockIdx.z;
    float Ad[DST], h[DST], ap[DST];
    #pragma unroll
    for (int s = 0; s < DST; ++s) {
        Ad[s] = -__expf(A_log[d * DST + s]);
        h[s] = 0.f; ap[s] = 1.f;
    }
    int i0 = g * Cn;
    for (int i = 0; i < Cn; ++i) {
        int ii = i0 + i;
        int t = dir ? (LL - 1 - ii) : ii;
        size_t m = (size_t)bb * LL + t;
        float dtv = dtf[m * DI + d];
        float xv  = xs[m * DI + d];
        const float* bc = xdb + m * 96;
        float dtx = dtv * xv;
        #pragma unroll
        for (int s = 0; s < DST; ++s) {
            float dA = __expf(dtv * Ad[s]);
            h[s] = fmaf(h[s], dA, dtx * bc[64 + s]);
            ap[s] *= dA;
        }
    }
    size_t base = ((size_t)(g * NB + bb) * DI + d) * DST;
    #pragma unroll
    for (int s = 0; s < DST; s += 4) {
        *(float4*)(hend  + base + s) = make_float4(h[s], h[s+1], h[s+2], h[s+3]);
        *(float4*)(aprod + base + s) = make_float4(ap[s], ap[s+1], ap[s+2], ap[s+3]);
    }
}

// carry combine: in-place hend -> h_in (entry state per chunk)
__global__ __launch_bounds__(256) void scan2_k(
    float* __restrict__ hend, const float* __restrict__ aprod, int G)
{
    int idx = blockIdx.x * 256 + threadIdx.x;   // (b,d,s) flat = NB*DI*DST
    float carry = 0.f;
    const int slab = NB * DI * DST;
    for (int g = 0; g < G; ++g) {
        size_t off = (size_t)g * slab + idx;
        float a = aprod[off];
        float e = hend[off];
        hend[off] = carry;           // entry state for chunk g
        carry = fmaf(a, carry, e);
    }
}

__global__ __launch_bounds__(256) void scan3_k(
    const float* __restrict__ dtf, const float* __restrict__ xs,
    const float* __restrict__ xdb, const float* __restrict__ xz,
    const float* __restrict__ A_log, const float* __restrict__ Dskip,
    const float* __restrict__ hin, float* __restrict__ y, int dir, int Cn)
{
    int d  = blockIdx.x * 256 + threadIdx.x;
    int bb = blockIdx.y;
    int g  = blockIdx.z;
    float Ad[DST], h[DST];
    size_t base = ((size_t)(g * NB + bb) * DI + d) * DST;
    #pragma unroll
    for (int s = 0; s < DST; ++s) {
        Ad[s] = -__expf(A_log[d * DST + s]);
        h[s] = hin[base + s];
    }
    float Dsk = Dskip[d];
    int i0 = g * Cn;
    for (int i = 0; i < Cn; ++i) {
        int ii = i0 + i;
        int t = dir ? (LL - 1 - ii) : ii;
        size_t m = (size_t)bb * LL + t;
        float dtv = dtf[m * DI + d];
        float xv  = xs[m * DI + d];
        const float* bc = xdb + m * 96;
        float dtx = dtv * xv;
        float yv = 0.f;
        #pragma unroll
        for (int s = 0; s < DST; ++s) {
            float dA = __expf(dtv * Ad[s]);
            h[s] = fmaf(h[s], dA, dtx * bc[64 + s]);
            yv = fmaf(h[s], bc[80 + s], yv);
        }
        float zv = xz[m * (2 * DI) + DI + d];
        y[m * DI + d] = (yv + xv * Dsk) * siluf(zv);
    }
}

// fallback: original monolithic scan (used only if ws too small for chunk bufs)
__global__ __launch_bounds__(256) void scan_k(
    const float* __restrict__ dtf, const float* __restrict__ xs,
    const float* __restrict__ xdb, const float* __restrict__ xz,
    const float* __restrict__ A_log, const float* __restrict__ Dskip,
    float* __restrict__ y, int dir)
{
    int d  = blockIdx.x * 256 + threadIdx.x;
    int bb = blockIdx.y;
    float Ad[DST];
    #pragma unroll
    for (int s = 0; s < DST; ++s) Ad[s] = -__expf(A_log[d * DST + s]);
    float Dsk = Dskip[d];
    float h[DST];
    #pragma unroll
    for (int s = 0; s < DST; ++s) h[s] = 0.f;
    for (int i = 0; i < LL; ++i) {
        int t = dir ? (LL - 1 - i) : i;
        size_t m = (size_t)bb * LL + t;
        float dtv = dtf[m * DI + d];
        float xv  = xs[m * DI + d];
        const float* bc = xdb + m * 96;
        float dtx = dtv * xv;
        float yv = 0.f;
        #pragma unroll
        for (int s = 0; s < DST; ++s) {
            float dA  = __expf(dtv * Ad[s]);
            float dBx = dtx * bc[64 + s];
            h[s] = fmaf(h[s], dA, dBx);
            yv = fmaf(h[s], bc[80 + s], yv);
        }
        float zv = xz[m * (2 * DI) + DI + d];
        y[m * DI + d] = (yv + xv * Dsk) * siluf(zv);
    }
}

// ---------------- Launch ----------------
extern "C" void kernel_launch(void* const* d_in, const int* in_sizes, int n_in,
                              void* d_out, int out_size, void* d_ws, size_t ws_size,
                              hipStream_t stream)
{
    const float* x      = (const float*)d_in[0];
    const float* ln_w   = (const float*)d_in[1];
    const float* ln_b   = (const float*)d_in[2];
    const float* proj_W = (const float*)d_in[21];
    const float* proj_b = (const float*)d_in[22];

    float* ws = (float*)d_ws;
    float* normed = ws;                                  // MR*DM
    float* xz     = normed + (size_t)MR * DM;            // MR*2*DI
    float* xs     = xz     + (size_t)MR * 2 * DI;        // MR*DI
    float* xdb    = xs     + (size_t)MR * DI;            // MR*96
    float* dtf    = xdb    + (size_t)MR * 96;            // MR*DI
    float* yb     = dtf    + (size_t)MR * DI;            // MR*DI
    float* comb   = yb     + (size_t)MR * DI;            // MR*2*DM
    float* hbuf   = comb   + (size_t)MR * 2 * DM;        // G*NB*DI*DST
    size_t base_floats = (size_t)(hbuf - ws);

    // pick largest chunk count G that fits in the workspace (host-side, constant
    // across calls -> graph-capture safe)
    const size_t slab = (size_t)NB * DI * DST;           // floats per chunk slab
    int G = 64;
    while (G >= 4 && (base_floats + 2 * (size_t)G * slab) * 4 > ws_size) G >>= 1;
    float* abuf = hbuf + (size_t)G * slab;
    int Cn = LL / (G >= 4 ? G : 1);

    layernorm_k<<<MR, 256, 0, stream>>>(x, ln_w, ln_b, normed);

    for (int dir = 0; dir < 2; ++dir) {
        const float* inW    = (const float*)d_in[3 + 9 * dir + 0];
        const float* convW  = (const float*)d_in[3 + 9 * dir + 1];
        const float* convb  = (const float*)d_in[3 + 9 * dir + 2];
        const float* xprojW = (const float*)d_in[3 + 9 * dir + 3];
        const float* dtW    = (const float*)d_in[3 + 9 * dir + 4];
        const float* dtb    = (const float*)d_in[3 + 9 * dir + 5];
        const float* A_log  = (const float*)d_in[3 + 9 * dir + 6];
        const float* Dskip  = (const float*)d_in[3 + 9 * dir + 7];
        const float* outW   = (const float*)d_in[3 + 9 * dir + 8];

        // xz = normed @ inW^T           [MR, 2*DI]
        gemm_abt<0><<<dim3((2 * DI) / 64, MR / 64), 256, 0, stream>>>(
            normed, DM, inW, DM, xz, 2 * DI, 2 * DI, DM, nullptr, nullptr, 0);

        // xs = silu(depthwise_conv(xz[:, :DI]))
        conv_silu_k<<<(MR * DI) / 256, 256, 0, stream>>>(xz, convW, convb, xs, dir);

        // xdb = xs @ xprojW^T           [MR, 96]
        gemm_abt<0><<<dim3((96 + 63) / 64, MR / 64), 256, 0, stream>>>(
            xs, DI, xprojW, DI, xdb, 96, 96, DI, nullptr, nullptr, 0);

        // dtf = softplus(xdb[:, :64] @ dtW^T + dtb)   [MR, DI]
        gemm_abt<1><<<dim3(DI / 64, MR / 64), 256, 0, stream>>>(
            xdb, 96, dtW, DTR, dtf, DI, DI, DTR, dtb, nullptr, 0);

        // selective scan
        if (G >= 4) {
            scan1_k<<<dim3(DI / 256, NB, G), 256, 0, stream>>>(
                dtf, xs, xdb, A_log, hbuf, abuf, dir, Cn);
            scan2_k<<<(NB * DI * DST) / 256, 256, 0, stream>>>(hbuf, abuf, G);
            scan3_k<<<dim3(DI / 256, NB, G), 256, 0, stream>>>(
                dtf, xs, xdb, xz, A_log, Dskip, hbuf, yb, dir, Cn);
        } else {
            scan_k<<<dim3(DI / 256, NB), 256, 0, stream>>>(
                dtf, xs, xdb, xz, A_log, Dskip, yb, dir);
        }

        // out-proj into the concat buffer: comb[:, dir*DM : dir*DM+DM]
        gemm_abt<0><<<dim3(DM / 64, MR / 64), 256, 0, stream>>>(
            yb, DI, outW, DI, comb + dir * DM, 2 * DM, DM, DI, nullptr, nullptr, 0);
    }

    // final: out = x + comb @ proj_W^T + proj_b
    gemm_abt<2><<<dim3(DM / 64, MR / 64), 256, 0, stream>>>(
        comb, 2 * DM, proj_W, 2 * DM, (float*)d_out, DM, DM, 2 * DM, proj_b, x, DM);
}

// Round 3
// 828.322 us; speedup vs baseline: 2.9843x; 1.8146x over previous
//
#include <hip/hip_runtime.h>
#include <hip/hip_bf16.h>
#include <math.h>

#define DM   1024   // d_model
#define DI   2048   // d_inner
#define DTR  64     // dt_rank
#define DST  16     // d_state
#define NB   2      // batch
#define LL   1024   // seq len
#define MR   (NB*LL)  // 2048 rows

typedef __bf16 bf16x8 __attribute__((ext_vector_type(8)));
typedef float  f32x4  __attribute__((ext_vector_type(4)));

__device__ __forceinline__ float siluf(float x) { return x / (1.f + __expf(-x)); }
__device__ __forceinline__ float softplusf(float x) {
    return fmaxf(x, 0.f) + log1pf(__expf(-fabsf(x)));
}
__device__ __forceinline__ unsigned short f2bf(float f) {
    __hip_bfloat16 h = __float2bfloat16(f);
    return *reinterpret_cast<unsigned short*>(&h);
}

// ---------------- LayerNorm -> bf16 output ----------------
__global__ __launch_bounds__(256) void layernorm_k(
    const float* __restrict__ x, const float* __restrict__ w,
    const float* __restrict__ b, __hip_bfloat16* __restrict__ out)
{
    int row = blockIdx.x;
    int tid = threadIdx.x;
    const float* xr = x + (size_t)row * DM;
    float4 v = *(const float4*)(xr + tid * 4);
    float s = v.x + v.y + v.z + v.w;
    float q = v.x*v.x + v.y*v.y + v.z*v.z + v.w*v.w;
    #pragma unroll
    for (int off = 32; off > 0; off >>= 1) {
        s += __shfl_xor(s, off, 64);
        q += __shfl_xor(q, off, 64);
    }
    __shared__ float ss[4], qq[4];
    int wv = tid >> 6;
    if ((tid & 63) == 0) { ss[wv] = s; qq[wv] = q; }
    __syncthreads();
    s = ss[0] + ss[1] + ss[2] + ss[3];
    q = qq[0] + qq[1] + qq[2] + qq[3];
    float mu  = s * (1.f / DM);
    float var = q * (1.f / DM) - mu * mu;
    float rstd = rsqrtf(var + 1e-5f);
    float4 wv4 = *(const float4*)(w + tid * 4);
    float4 bv4 = *(const float4*)(b + tid * 4);
    ushort4 o;
    o.x = f2bf((v.x - mu) * rstd * wv4.x + bv4.x);
    o.y = f2bf((v.y - mu) * rstd * wv4.y + bv4.y);
    o.z = f2bf((v.z - mu) * rstd * wv4.z + bv4.z);
    o.w = f2bf((v.w - mu) * rstd * wv4.w + bv4.w);
    *(ushort4*)((unsigned short*)out + (size_t)row * DM + tid * 4) = o;
}

// ---------------- fp32 -> bf16 conversion (n multiple of 1024) ----------------
__global__ __launch_bounds__(256) void cvt_bf16_k(
    const float* __restrict__ in, __hip_bfloat16* __restrict__ out)
{
    int idx = (blockIdx.x * 256 + threadIdx.x) * 4;
    float4 v = *(const float4*)(in + idx);
    ushort4 o;
    o.x = f2bf(v.x); o.y = f2bf(v.y); o.z = f2bf(v.z); o.w = f2bf(v.w);
    *(ushort4*)((unsigned short*)out + idx) = o;
}

// ---------------- bf16 MFMA GEMM: C[m,n] = sum_k A[m,k]*B[n,k] ----------------
// 128x128 tile, BK=32, 256 threads (4 waves, each 64x64).
// EPI: 0 = fp32 store, 1 = bf16 store, 2 = fp32 + bias[n] + res[m,n]
// M,N multiples of 128; K multiple of 32.
#define LDP 40   // LDS row pitch in bf16 (pad 32->40 kills bank conflicts)
template<int EPI>
__global__ __launch_bounds__(256) void gemm_mfma(
    const __hip_bfloat16* __restrict__ A, int lda,
    const __hip_bfloat16* __restrict__ B, int ldb,
    void* __restrict__ Cp, int ldc, int K,
    const float* __restrict__ bias,
    const float* __restrict__ res, int ldres)
{
    __shared__ __hip_bfloat16 As[128 * LDP];
    __shared__ __hip_bfloat16 Bs[128 * LDP];
    const int tid  = threadIdx.x;
    const int bm   = blockIdx.y * 128;
    const int bn   = blockIdx.x * 128;
    const int wv   = tid >> 6;
    const int lane = tid & 63;
    const int wr   = (wv >> 1) * 64;   // wave row offset
    const int wc   = (wv & 1) * 64;    // wave col offset
    const int fr   = lane & 15;        // fragment row
    const int fk   = (lane >> 4) * 8;  // fragment k offset
    const int sr   = tid >> 1;         // staging row 0..127
    const int sc   = (tid & 1) * 16;   // staging col (bf16 units)

    f32x4 acc[4][4] = {};

    for (int k0 = 0; k0 < K; k0 += 32) {
        const float4* ag = (const float4*)(A + (size_t)(bm + sr) * lda + k0 + sc);
        const float4* bg = (const float4*)(B + (size_t)(bn + sr) * ldb + k0 + sc);
        float4 a0 = ag[0], a1 = ag[1];
        float4 b0 = bg[0], b1 = bg[1];
        __syncthreads();
        *(float4*)(As + sr * LDP + sc)     = a0;
        *(float4*)(As + sr * LDP + sc + 8) = a1;
        *(float4*)(Bs + sr * LDP + sc)     = b0;
        *(float4*)(Bs + sr * LDP + sc + 8) = b1;
        __syncthreads();
        bf16x8 af[4], bfr[4];
        #pragma unroll
        for (int i = 0; i < 4; ++i) {
            af[i]  = *(const bf16x8*)(As + (wr + i * 16 + fr) * LDP + fk);
            bfr[i] = *(const bf16x8*)(Bs + (wc + i * 16 + fr) * LDP + fk);
        }
        #pragma unroll
        for (int i = 0; i < 4; ++i)
            #pragma unroll
            for (int j = 0; j < 4; ++j)
                acc[i][j] = __builtin_amdgcn_mfma_f32_16x16x32_bf16(
                    af[i], bfr[j], acc[i][j], 0, 0, 0);
    }

    const int er = (lane >> 4) * 4;    // C/D: row = quad*4+reg, col = lane&15
    const int ec = lane & 15;
    #pragma unroll
    for (int i = 0; i < 4; ++i) {
        #pragma unroll
        for (int j = 0; j < 4; ++j) {
            int row = bm + wr + i * 16 + er;
            int col = bn + wc + j * 16 + ec;
            #pragma unroll
            for (int r = 0; r < 4; ++r) {
                float v = acc[i][j][r];
                if (EPI == 1) {
                    ((__hip_bfloat16*)Cp)[(size_t)(row + r) * ldc + col] =
                        __float2bfloat16(v);
                } else if (EPI == 2) {
                    ((float*)Cp)[(size_t)(row + r) * ldc + col] =
                        v + bias[col] + res[(size_t)(row + r) * ldres + col];
                } else {
                    ((float*)Cp)[(size_t)(row + r) * ldc + col] = v;
                }
            }
        }
    }
}

// ---------------- Generic fp32 GEMM (small shapes: xproj, dt-proj) ----------------
template<int EPI>
__device__ __forceinline__ float epi_apply(float t, int col, const float* bias)
{
    if (EPI == 1) t = softplusf(t + bias[col]);
    return t;
}

template<int EPI>
__global__ __launch_bounds__(256) void gemm_abt(
    const float* __restrict__ A, int lda,
    const float* __restrict__ B, int ldb,
    float* __restrict__ C, int ldc,
    int N, int K,
    const float* __restrict__ bias)
{
    __shared__ float As[16][68];
    __shared__ float Bs[16][68];
    const int tid = threadIdx.x;
    const int bm = blockIdx.y * 64;
    const int bn = blockIdx.x * 64;
    const int lr = tid >> 2;
    const int lk = (tid & 3) << 2;
    const int tx = tid & 15;
    const int ty = tid >> 4;
    float acc[4][4] = {};

    for (int k0 = 0; k0 < K; k0 += 16) {
        float4 av = *(const float4*)(A + (size_t)(bm + lr) * lda + (k0 + lk));
        float4 bv = make_float4(0.f, 0.f, 0.f, 0.f);
        if (bn + lr < N)
            bv = *(const float4*)(B + (size_t)(bn + lr) * ldb + (k0 + lk));
        As[lk+0][lr] = av.x; As[lk+1][lr] = av.y; As[lk+2][lr] = av.z; As[lk+3][lr] = av.w;
        Bs[lk+0][lr] = bv.x; Bs[lk+1][lr] = bv.y; Bs[lk+2][lr] = bv.z; Bs[lk+3][lr] = bv.w;
        __syncthreads();
        #pragma unroll
        for (int kk = 0; kk < 16; ++kk) {
            float4 a4 = *(const float4*)&As[kk][ty << 2];
            float4 b4 = *(const float4*)&Bs[kk][tx << 2];
            float a[4] = {a4.x, a4.y, a4.z, a4.w};
            float b[4] = {b4.x, b4.y, b4.z, b4.w};
            #pragma unroll
            for (int i = 0; i < 4; ++i)
                #pragma unroll
                for (int j = 0; j < 4; ++j)
                    acc[i][j] = fmaf(a[i], b[j], acc[i][j]);
        }
        __syncthreads();
    }

    #pragma unroll
    for (int i = 0; i < 4; ++i) {
        int row  = bm + (ty << 2) + i;
        int col0 = bn + (tx << 2);
        #pragma unroll
        for (int j = 0; j < 4; ++j) {
            int col = col0 + j;
            if (col < N)
                C[(size_t)row * ldc + col] = epi_apply<EPI>(acc[i][j], col, bias);
        }
    }
}

// ---------------- Depthwise conv (width 4) + SiLU ----------------
__global__ __launch_bounds__(256) void conv_silu_k(
    const float* __restrict__ xz, const float* __restrict__ convW,
    const float* __restrict__ convb, float* __restrict__ xs, int dir)
{
    int idx = blockIdx.x * 256 + threadIdx.x;
    int d = idx & (DI - 1);
    int m = idx >> 11;
    int t = m & (LL - 1);
    int bb = m >> 10;
    const float* w = convW + d * 4;
    float acc = convb[d];
    if (dir == 0) {
        #pragma unroll
        for (int k = 0; k < 4; ++k) {
            int tt = t - 3 + k;
            if (tt >= 0)
                acc = fmaf(w[k], xz[(size_t)(bb * LL + tt) * (2 * DI) + d], acc);
        }
    } else {
        #pragma unroll
        for (int k = 0; k < 4; ++k) {
            int tt = t + 3 - k;
            if (tt < LL)
                acc = fmaf(w[k], xz[(size_t)(bb * LL + tt) * (2 * DI) + d], acc);
        }
    }
    xs[(size_t)m * DI + d] = siluf(acc);
}

// ---------------- Chunked selective scan ----------------
__global__ __launch_bounds__(256) void scan1_k(
    const float* __restrict__ dtf, const float* __restrict__ xs,
    const float* __restrict__ xdb, const float* __restrict__ A_log,
    float* __restrict__ hend, float* __restrict__ aprod, int dir, int Cn)
{
    int d  = blockIdx.x * 256 + threadIdx.x;
    int bb = blockIdx.y;
    int g  = blockIdx.z;
    float Ad[DST], h[DST], ap[DST];
    #pragma unroll
    for (int s = 0; s < DST; ++s) {
        Ad[s] = -__expf(A_log[d * DST + s]);
        h[s] = 0.f; ap[s] = 1.f;
    }
    int i0 = g * Cn;
    for (int i = 0; i < Cn; ++i) {
        int ii = i0 + i;
        int t = dir ? (LL - 1 - ii) : ii;
        size_t m = (size_t)bb * LL + t;
        float dtv = dtf[m * DI + d];
        float xv  = xs[m * DI + d];
        const float* bc = xdb + m * 96;
        float dtx = dtv * xv;
        #pragma unroll
        for (int s = 0; s < DST; ++s) {
            float dA = __expf(dtv * Ad[s]);
            h[s] = fmaf(h[s], dA, dtx * bc[64 + s]);
            ap[s] *= dA;
        }
    }
    size_t base = ((size_t)(g * NB + bb) * DI + d) * DST;
    #pragma unroll
    for (int s = 0; s < DST; s += 4) {
        *(float4*)(hend  + base + s) = make_float4(h[s], h[s+1], h[s+2], h[s+3]);
        *(float4*)(aprod + base + s) = make_float4(ap[s], ap[s+1], ap[s+2], ap[s+3]);
    }
}

__global__ __launch_bounds__(256) void scan2_k(
    float* __restrict__ hend, const float* __restrict__ aprod, int G)
{
    int idx = blockIdx.x * 256 + threadIdx.x;
    float carry = 0.f;
    const int slab = NB * DI * DST;
    for (int g = 0; g < G; ++g) {
        size_t off = (size_t)g * slab + idx;
        float a = aprod[off];
        float e = hend[off];
        hend[off] = carry;
        carry = fmaf(a, carry, e);
    }
}

__global__ __launch_bounds__(256) void scan3_k(
    const float* __restrict__ dtf, const float* __restrict__ xs,
    const float* __restrict__ xdb, const float* __restrict__ xz,
    const float* __restrict__ A_log, const float* __restrict__ Dskip,
    const float* __restrict__ hin, __hip_bfloat16* __restrict__ y, int dir, int Cn)
{
    int d  = blockIdx.x * 256 + threadIdx.x;
    int bb = blockIdx.y;
    int g  = blockIdx.z;
    float Ad[DST], h[DST];
    size_t base = ((size_t)(g * NB + bb) * DI + d) * DST;
    #pragma unroll
    for (int s = 0; s < DST; ++s) {
        Ad[s] = -__expf(A_log[d * DST + s]);
        h[s] = hin[base + s];
    }
    float Dsk = Dskip[d];
    int i0 = g * Cn;
    for (int i = 0; i < Cn; ++i) {
        int ii = i0 + i;
        int t = dir ? (LL - 1 - ii) : ii;
        size_t m = (size_t)bb * LL + t;
        float dtv = dtf[m * DI + d];
        float xv  = xs[m * DI + d];
        const float* bc = xdb + m * 96;
        float dtx = dtv * xv;
        float yv = 0.f;
        #pragma unroll
        for (int s = 0; s < DST; ++s) {
            float dA = __expf(dtv * Ad[s]);
            h[s] = fmaf(h[s], dA, dtx * bc[64 + s]);
            yv = fmaf(h[s], bc[80 + s], yv);
        }
        float zv = xz[m * (2 * DI) + DI + d];
        y[m * DI + d] = __float2bfloat16((yv + xv * Dsk) * siluf(zv));
    }
}

// fallback monolithic scan (if ws too small for chunk bufs)
__global__ __launch_bounds__(256) void scan_k(
    const float* __restrict__ dtf, const float* __restrict__ xs,
    const float* __restrict__ xdb, const float* __restrict__ xz,
    const float* __restrict__ A_log, const float* __restrict__ Dskip,
    __hip_bfloat16* __restrict__ y, int dir)
{
    int d  = blockIdx.x * 256 + threadIdx.x;
    int bb = blockIdx.y;
    float Ad[DST];
    #pragma unroll
    for (int s = 0; s < DST; ++s) Ad[s] = -__expf(A_log[d * DST + s]);
    float Dsk = Dskip[d];
    float h[DST];
    #pragma unroll
    for (int s = 0; s < DST; ++s) h[s] = 0.f;
    for (int i = 0; i < LL; ++i) {
        int t = dir ? (LL - 1 - i) : i;
        size_t m = (size_t)bb * LL + t;
        float dtv = dtf[m * DI + d];
        float xv  = xs[m * DI + d];
        const float* bc = xdb + m * 96;
        float dtx = dtv * xv;
        float yv = 0.f;
        #pragma unroll
        for (int s = 0; s < DST; ++s) {
            float dA  = __expf(dtv * Ad[s]);
            h[s] = fmaf(h[s], dA, dtx * bc[64 + s]);
            yv = fmaf(h[s], bc[80 + s], yv);
        }
        float zv = xz[m * (2 * DI) + DI + d];
        y[m * DI + d] = __float2bfloat16((yv + xv * Dsk) * siluf(zv));
    }
}

// ---------------- Launch ----------------
extern "C" void kernel_launch(void* const* d_in, const int* in_sizes, int n_in,
                              void* d_out, int out_size, void* d_ws, size_t ws_size,
                              hipStream_t stream)
{
    const float* x      = (const float*)d_in[0];
    const float* ln_w   = (const float*)d_in[1];
    const float* ln_b   = (const float*)d_in[2];
    const float* proj_W = (const float*)d_in[21];
    const float* proj_b = (const float*)d_in[22];

    float* ws = (float*)d_ws;
    // fp32 buffers
    float* xz  = ws;                                  // MR*2*DI   = 8388608
    float* xs  = xz  + (size_t)MR * 2 * DI;           // MR*DI     = 4194304
    float* xdb = xs  + (size_t)MR * DI;               // MR*96     = 196608
    float* dtf = xdb + (size_t)MR * 96;               // MR*DI     = 4194304
    // bf16 buffers (sized in float units: elems/2)
    float* p = dtf + (size_t)MR * DI;
    __hip_bfloat16* nb  = (__hip_bfloat16*)p; p += (size_t)MR * DM / 2;      // normed bf16
    __hip_bfloat16* wb  = (__hip_bfloat16*)p; p += (size_t)2 * DI * DM / 2;  // weight bf16 (max 4M)
    __hip_bfloat16* ab  = (__hip_bfloat16*)p; p += (size_t)MR * DI / 2;      // y bf16
    __hip_bfloat16* cb  = (__hip_bfloat16*)p; p += (size_t)MR * 2 * DM / 2;  // comb bf16
    __hip_bfloat16* pwb = (__hip_bfloat16*)p; p += (size_t)DM * 2 * DM / 2;  // proj_W bf16
    float* hbuf = p;
    size_t base_floats = (size_t)(hbuf - ws);

    const size_t slab = (size_t)NB * DI * DST;
    int G = 64;
    while (G >= 4 && (base_floats + 2 * (size_t)G * slab) * 4 > ws_size) G >>= 1;
    int useChunks = (G >= 4);
    float* abuf = hbuf + (size_t)G * slab;
    int Cn = useChunks ? LL / G : LL;

    layernorm_k<<<MR, 256, 0, stream>>>(x, ln_w, ln_b, nb);

    for (int dir = 0; dir < 2; ++dir) {
        const float* inW    = (const float*)d_in[3 + 9 * dir + 0];
        const float* convW  = (const float*)d_in[3 + 9 * dir + 1];
        const float* convb  = (const float*)d_in[3 + 9 * dir + 2];
        const float* xprojW = (const float*)d_in[3 + 9 * dir + 3];
        const float* dtW    = (const float*)d_in[3 + 9 * dir + 4];
        const float* dtb    = (const float*)d_in[3 + 9 * dir + 5];
        const float* A_log  = (const float*)d_in[3 + 9 * dir + 6];
        const float* Dskip  = (const float*)d_in[3 + 9 * dir + 7];
        const float* outW   = (const float*)d_in[3 + 9 * dir + 8];

        // inW -> bf16 ; xz = nb @ inW^T  [MR, 2*DI] fp32
        cvt_bf16_k<<<(2 * DI * DM) / 1024, 256, 0, stream>>>(inW, wb);
        gemm_mfma<0><<<dim3((2 * DI) / 128, MR / 128), 256, 0, stream>>>(
            nb, DM, wb, DM, xz, 2 * DI, DM, nullptr, nullptr, 0);

        // xs = silu(depthwise_conv(xz[:, :DI]))
        conv_silu_k<<<(MR * DI) / 256, 256, 0, stream>>>(xz, convW, convb, xs, dir);

        // xdb = xs @ xprojW^T  [MR, 96] fp32
        gemm_abt<0><<<dim3(2, MR / 64), 256, 0, stream>>>(
            xs, DI, xprojW, DI, xdb, 96, 96, DI, nullptr);

        // dtf = softplus(xdb[:, :64] @ dtW^T + dtb)  [MR, DI] fp32
        gemm_abt<1><<<dim3(DI / 64, MR / 64), 256, 0, stream>>>(
            xdb, 96, dtW, DTR, dtf, DI, DI, DTR, dtb);

        // selective scan -> ab (bf16)
        if (useChunks) {
            scan1_k<<<dim3(DI / 256, NB, G), 256, 0, stream>>>(
                dtf, xs, xdb, A_log, hbuf, abuf, dir, Cn);
            scan2_k<<<(NB * DI * DST) / 256, 256, 0, stream>>>(hbuf, abuf, G);
            scan3_k<<<dim3(DI / 256, NB, G), 256, 0, stream>>>(
                dtf, xs, xdb, xz, A_log, Dskip, hbuf, ab, dir, Cn);
        } else {
            scan_k<<<dim3(DI / 256, NB), 256, 0, stream>>>(
                dtf, xs, xdb, xz, A_log, Dskip, ab, dir);
        }

        // outW -> bf16 ; comb[:, dir*DM:+DM] = ab @ outW^T (bf16 store)
        cvt_bf16_k<<<(DM * DI) / 1024, 256, 0, stream>>>(outW, wb);
        gemm_mfma<1><<<dim3(DM / 128, MR / 128), 256, 0, stream>>>(
            ab, DI, wb, DI, cb + dir * DM, 2 * DM, DI, nullptr, nullptr, 0);
    }

    // final: out = x + cb @ proj_W^T + proj_b  (fp32 out)
    cvt_bf16_k<<<(DM * 2 * DM) / 1024, 256, 0, stream>>>(proj_W, pwb);
    gemm_mfma<2><<<dim3(DM / 128, MR / 128), 256, 0, stream>>>(
        cb, 2 * DM, pwb, 2 * DM, (float*)d_out, DM, 2 * DM, proj_b, x, DM);
}

// Round 4
// 638.918 us; speedup vs baseline: 3.8690x; 1.2964x over previous
//
#include <hip/hip_runtime.h>
#include <hip/hip_bf16.h>
#include <math.h>

#define DM   1024   // d_model
#define DI   2048   // d_inner
#define DTR  64     // dt_rank
#define DST  16     // d_state
#define NB   2      // batch
#define LL   1024   // seq len
#define MR   (NB*LL)  // 2048 rows
#define XLD  128    // xdb padded leading dim
#define KS   16     // split-K factor for x-proj

typedef __bf16 bf16x8 __attribute__((ext_vector_type(8)));
typedef float  f32x4  __attribute__((ext_vector_type(4)));

__device__ __forceinline__ float siluf(float x) { return x / (1.f + __expf(-x)); }
__device__ __forceinline__ float softplusf(float x) {
    return fmaxf(x, 0.f) + log1pf(__expf(-fabsf(x)));
}
__device__ __forceinline__ unsigned short f2bf(float f) {
    __hip_bfloat16 h = __float2bfloat16(f);
    return *reinterpret_cast<unsigned short*>(&h);
}

// ---------------- LayerNorm -> bf16 output ----------------
__global__ __launch_bounds__(256) void layernorm_k(
    const float* __restrict__ x, const float* __restrict__ w,
    const float* __restrict__ b, __hip_bfloat16* __restrict__ out)
{
    int row = blockIdx.x;
    int tid = threadIdx.x;
    const float* xr = x + (size_t)row * DM;
    float4 v = *(const float4*)(xr + tid * 4);
    float s = v.x + v.y + v.z + v.w;
    float q = v.x*v.x + v.y*v.y + v.z*v.z + v.w*v.w;
    #pragma unroll
    for (int off = 32; off > 0; off >>= 1) {
        s += __shfl_xor(s, off, 64);
        q += __shfl_xor(q, off, 64);
    }
    __shared__ float ss[4], qq[4];
    int wv = tid >> 6;
    if ((tid & 63) == 0) { ss[wv] = s; qq[wv] = q; }
    __syncthreads();
    s = ss[0] + ss[1] + ss[2] + ss[3];
    q = qq[0] + qq[1] + qq[2] + qq[3];
    float mu  = s * (1.f / DM);
    float var = q * (1.f / DM) - mu * mu;
    float rstd = rsqrtf(var + 1e-5f);
    float4 wv4 = *(const float4*)(w + tid * 4);
    float4 bv4 = *(const float4*)(b + tid * 4);
    ushort4 o;
    o.x = f2bf((v.x - mu) * rstd * wv4.x + bv4.x);
    o.y = f2bf((v.y - mu) * rstd * wv4.y + bv4.y);
    o.z = f2bf((v.z - mu) * rstd * wv4.z + bv4.z);
    o.w = f2bf((v.w - mu) * rstd * wv4.w + bv4.w);
    *(ushort4*)((unsigned short*)out + (size_t)row * DM + tid * 4) = o;
}

// ---------------- fp32 -> bf16 (flat, n multiple of 1024) ----------------
__global__ __launch_bounds__(256) void cvt_bf16_k(
    const float* __restrict__ in, __hip_bfloat16* __restrict__ out)
{
    int idx = (blockIdx.x * 256 + threadIdx.x) * 4;
    float4 v = *(const float4*)(in + idx);
    ushort4 o;
    o.x = f2bf(v.x); o.y = f2bf(v.y); o.z = f2bf(v.z); o.w = f2bf(v.w);
    *(ushort4*)((unsigned short*)out + idx) = o;
}

// ---------------- xprojW (96x2048 fp32) -> bf16 padded to 128 rows ----------------
__global__ __launch_bounds__(256) void cvt_pad96_k(
    const float* __restrict__ in, __hip_bfloat16* __restrict__ out)
{
    int idx = (blockIdx.x * 256 + threadIdx.x) * 4;   // over 128*2048
    int row = idx >> 11;
    ushort4 o = make_ushort4(0, 0, 0, 0);
    if (row < 96) {
        float4 v = *(const float4*)(in + idx);
        o.x = f2bf(v.x); o.y = f2bf(v.y); o.z = f2bf(v.z); o.w = f2bf(v.w);
    }
    *(ushort4*)((unsigned short*)out + idx) = o;
}

// ---------------- bf16 MFMA GEMM: C[m,n] = sum_k A[m,k]*B[n,k] ----------------
// 128x128 tile, BK=32, 256 threads (4 waves, each 64x64).
// EPI: 0 = fp32 store, 1 = bf16 store, 2 = fp32 + bias[n] + res[m,n]
#define LDP 40   // LDS row pitch in bf16
template<int EPI>
__global__ __launch_bounds__(256) void gemm_mfma(
    const __hip_bfloat16* __restrict__ A, int lda,
    const __hip_bfloat16* __restrict__ B, int ldb,
    void* __restrict__ Cp, int ldc, int K,
    const float* __restrict__ bias,
    const float* __restrict__ res, int ldres)
{
    __shared__ __hip_bfloat16 As[128 * LDP];
    __shared__ __hip_bfloat16 Bs[128 * LDP];
    const int tid  = threadIdx.x;
    const int bm   = blockIdx.y * 128;
    const int bn   = blockIdx.x * 128;
    const int wv   = tid >> 6;
    const int lane = tid & 63;
    const int wr   = (wv >> 1) * 64;
    const int wc   = (wv & 1) * 64;
    const int fr   = lane & 15;
    const int fk   = (lane >> 4) * 8;
    const int sr   = tid >> 1;
    const int sc   = (tid & 1) * 16;

    f32x4 acc[4][4] = {};

    for (int k0 = 0; k0 < K; k0 += 32) {
        const float4* ag = (const float4*)(A + (size_t)(bm + sr) * lda + k0 + sc);
        const float4* bg = (const float4*)(B + (size_t)(bn + sr) * ldb + k0 + sc);
        float4 a0 = ag[0], a1 = ag[1];
        float4 b0 = bg[0], b1 = bg[1];
        __syncthreads();
        *(float4*)(As + sr * LDP + sc)     = a0;
        *(float4*)(As + sr * LDP + sc + 8) = a1;
        *(float4*)(Bs + sr * LDP + sc)     = b0;
        *(float4*)(Bs + sr * LDP + sc + 8) = b1;
        __syncthreads();
        bf16x8 af[4], bfr[4];
        #pragma unroll
        for (int i = 0; i < 4; ++i) {
            af[i]  = *(const bf16x8*)(As + (wr + i * 16 + fr) * LDP + fk);
            bfr[i] = *(const bf16x8*)(Bs + (wc + i * 16 + fr) * LDP + fk);
        }
        #pragma unroll
        for (int i = 0; i < 4; ++i)
            #pragma unroll
            for (int j = 0; j < 4; ++j)
                acc[i][j] = __builtin_amdgcn_mfma_f32_16x16x32_bf16(
                    af[i], bfr[j], acc[i][j], 0, 0, 0);
    }

    const int er = (lane >> 4) * 4;
    const int ec = lane & 15;
    #pragma unroll
    for (int i = 0; i < 4; ++i) {
        #pragma unroll
        for (int j = 0; j < 4; ++j) {
            int row = bm + wr + i * 16 + er;
            int col = bn + wc + j * 16 + ec;
            #pragma unroll
            for (int r = 0; r < 4; ++r) {
                float v = acc[i][j][r];
                if (EPI == 1) {
                    ((__hip_bfloat16*)Cp)[(size_t)(row + r) * ldc + col] =
                        __float2bfloat16(v);
                } else if (EPI == 2) {
                    ((float*)Cp)[(size_t)(row + r) * ldc + col] =
                        v + bias[col] + res[(size_t)(row + r) * ldres + col];
                } else {
                    ((float*)Cp)[(size_t)(row + r) * ldc + col] = v;
                }
            }
        }
    }
}

// ---------------- x-proj split-K partials: part[ks][MR][128] ----------------
// A = xs bf16 [MR, DI], B = wpb bf16 [128, DI] (rows 96..127 zero).
// Block (ks, mb): 128x128 tile over K-slice [ks*128, ks*128+128).
__global__ __launch_bounds__(256) void xproj_part_k(
    const __hip_bfloat16* __restrict__ A,
    const __hip_bfloat16* __restrict__ B,
    float* __restrict__ part)
{
    __shared__ __hip_bfloat16 As[128 * LDP];
    __shared__ __hip_bfloat16 Bs[128 * LDP];
    const int tid  = threadIdx.x;
    const int ks   = blockIdx.x;
    const int bm   = blockIdx.y * 128;
    const int kb   = ks * 128;
    const int wv   = tid >> 6;
    const int lane = tid & 63;
    const int wr   = (wv >> 1) * 64;
    const int wc   = (wv & 1) * 64;
    const int fr   = lane & 15;
    const int fk   = (lane >> 4) * 8;
    const int sr   = tid >> 1;
    const int sc   = (tid & 1) * 16;

    f32x4 acc[4][4] = {};

    #pragma unroll
    for (int k0 = 0; k0 < 128; k0 += 32) {
        const float4* ag = (const float4*)(A + (size_t)(bm + sr) * DI + kb + k0 + sc);
        const float4* bg = (const float4*)(B + (size_t)sr * DI + kb + k0 + sc);
        float4 a0 = ag[0], a1 = ag[1];
        float4 b0 = bg[0], b1 = bg[1];
        __syncthreads();
        *(float4*)(As + sr * LDP + sc)     = a0;
        *(float4*)(As + sr * LDP + sc + 8) = a1;
        *(float4*)(Bs + sr * LDP + sc)     = b0;
        *(float4*)(Bs + sr * LDP + sc + 8) = b1;
        __syncthreads();
        bf16x8 af[4], bfr[4];
        #pragma unroll
        for (int i = 0; i < 4; ++i) {
            af[i]  = *(const bf16x8*)(As + (wr + i * 16 + fr) * LDP + fk);
            bfr[i] = *(const bf16x8*)(Bs + (wc + i * 16 + fr) * LDP + fk);
        }
        #pragma unroll
        for (int i = 0; i < 4; ++i)
            #pragma unroll
            for (int j = 0; j < 4; ++j)
                acc[i][j] = __builtin_amdgcn_mfma_f32_16x16x32_bf16(
                    af[i], bfr[j], acc[i][j], 0, 0, 0);
    }

    float* dst = part + (size_t)ks * MR * XLD;
    const int er = (lane >> 4) * 4;
    const int ec = lane & 15;
    #pragma unroll
    for (int i = 0; i < 4; ++i)
        #pragma unroll
        for (int j = 0; j < 4; ++j) {
            int row = bm + wr + i * 16 + er;
            int col = wc + j * 16 + ec;
            #pragma unroll
            for (int r = 0; r < 4; ++r)
                dst[(size_t)(row + r) * XLD + col] = acc[i][j][r];
        }
}

// ---------------- reduce KS partial slabs -> xdb_pad ----------------
__global__ __launch_bounds__(256) void xproj_reduce_k(
    const float* __restrict__ part, float* __restrict__ xdb)
{
    int idx = (blockIdx.x * 256 + threadIdx.x) * 4;   // over MR*XLD
    float4 s = make_float4(0.f, 0.f, 0.f, 0.f);
    #pragma unroll
    for (int ks = 0; ks < KS; ++ks) {
        float4 v = *(const float4*)(part + (size_t)ks * MR * XLD + idx);
        s.x += v.x; s.y += v.y; s.z += v.z; s.w += v.w;
    }
    *(float4*)(xdb + idx) = s;
}

// ---------------- Generic fp32 GEMM (dt-proj only) ----------------
template<int EPI>
__device__ __forceinline__ float epi_apply(float t, int col, const float* bias)
{
    if (EPI == 1) t = softplusf(t + bias[col]);
    return t;
}

template<int EPI>
__global__ __launch_bounds__(256) void gemm_abt(
    const float* __restrict__ A, int lda,
    const float* __restrict__ B, int ldb,
    float* __restrict__ C, int ldc,
    int N, int K,
    const float* __restrict__ bias)
{
    __shared__ float As[16][68];
    __shared__ float Bs[16][68];
    const int tid = threadIdx.x;
    const int bm = blockIdx.y * 64;
    const int bn = blockIdx.x * 64;
    const int lr = tid >> 2;
    const int lk = (tid & 3) << 2;
    const int tx = tid & 15;
    const int ty = tid >> 4;
    float acc[4][4] = {};

    for (int k0 = 0; k0 < K; k0 += 16) {
        float4 av = *(const float4*)(A + (size_t)(bm + lr) * lda + (k0 + lk));
        float4 bv = make_float4(0.f, 0.f, 0.f, 0.f);
        if (bn + lr < N)
            bv = *(const float4*)(B + (size_t)(bn + lr) * ldb + (k0 + lk));
        As[lk+0][lr] = av.x; As[lk+1][lr] = av.y; As[lk+2][lr] = av.z; As[lk+3][lr] = av.w;
        Bs[lk+0][lr] = bv.x; Bs[lk+1][lr] = bv.y; Bs[lk+2][lr] = bv.z; Bs[lk+3][lr] = bv.w;
        __syncthreads();
        #pragma unroll
        for (int kk = 0; kk < 16; ++kk) {
            float4 a4 = *(const float4*)&As[kk][ty << 2];
            float4 b4 = *(const float4*)&Bs[kk][tx << 2];
            float a[4] = {a4.x, a4.y, a4.z, a4.w};
            float b[4] = {b4.x, b4.y, b4.z, b4.w};
            #pragma unroll
            for (int i = 0; i < 4; ++i)
                #pragma unroll
                for (int j = 0; j < 4; ++j)
                    acc[i][j] = fmaf(a[i], b[j], acc[i][j]);
        }
        __syncthreads();
    }

    #pragma unroll
    for (int i = 0; i < 4; ++i) {
        int row  = bm + (ty << 2) + i;
        int col0 = bn + (tx << 2);
        #pragma unroll
        for (int j = 0; j < 4; ++j) {
            int col = col0 + j;
            if (col < N)
                C[(size_t)row * ldc + col] = epi_apply<EPI>(acc[i][j], col, bias);
        }
    }
}

// ---------------- Depthwise conv (width 4) + SiLU, dual fp32/bf16 store ----------------
__global__ __launch_bounds__(256) void conv_silu_k(
    const float* __restrict__ xz, const float* __restrict__ convW,
    const float* __restrict__ convb, float* __restrict__ xs,
    __hip_bfloat16* __restrict__ xsb, int dir)
{
    int idx = blockIdx.x * 256 + threadIdx.x;
    int d = idx & (DI - 1);
    int m = idx >> 11;
    int t = m & (LL - 1);
    int bb = m >> 10;
    const float* w = convW + d * 4;
    float acc = convb[d];
    if (dir == 0) {
        #pragma unroll
        for (int k = 0; k < 4; ++k) {
            int tt = t - 3 + k;
            if (tt >= 0)
                acc = fmaf(w[k], xz[(size_t)(bb * LL + tt) * (2 * DI) + d], acc);
        }
    } else {
        #pragma unroll
        for (int k = 0; k < 4; ++k) {
            int tt = t + 3 - k;
            if (tt < LL)
                acc = fmaf(w[k], xz[(size_t)(bb * LL + tt) * (2 * DI) + d], acc);
        }
    }
    float v = siluf(acc);
    xs[(size_t)m * DI + d]  = v;
    xsb[(size_t)m * DI + d] = __float2bfloat16(v);
}

// ---------------- Chunked selective scan (xdb stride = XLD) ----------------
__global__ __launch_bounds__(256) void scan1_k(
    const float* __restrict__ dtf, const float* __restrict__ xs,
    const float* __restrict__ xdb, const float* __restrict__ A_log,
    float* __restrict__ hend, float* __restrict__ aprod, int dir, int Cn)
{
    int d  = blockIdx.x * 256 + threadIdx.x;
    int bb = blockIdx.y;
    int g  = blockIdx.z;
    float Ad[DST], h[DST], ap[DST];
    #pragma unroll
    for (int s = 0; s < DST; ++s) {
        Ad[s] = -__expf(A_log[d * DST + s]);
        h[s] = 0.f; ap[s] = 1.f;
    }
    int i0 = g * Cn;
    for (int i = 0; i < Cn; ++i) {
        int ii = i0 + i;
        int t = dir ? (LL - 1 - ii) : ii;
        size_t m = (size_t)bb * LL + t;
        float dtv = dtf[m * DI + d];
        float xv  = xs[m * DI + d];
        const float* bc = xdb + m * XLD;
        float dtx = dtv * xv;
        #pragma unroll
        for (int s = 0; s < DST; ++s) {
            float dA = __expf(dtv * Ad[s]);
            h[s] = fmaf(h[s], dA, dtx * bc[64 + s]);
            ap[s] *= dA;
        }
    }
    size_t base = ((size_t)(g * NB + bb) * DI + d) * DST;
    #pragma unroll
    for (int s = 0; s < DST; s += 4) {
        *(float4*)(hend  + base + s) = make_float4(h[s], h[s+1], h[s+2], h[s+3]);
        *(float4*)(aprod + base + s) = make_float4(ap[s], ap[s+1], ap[s+2], ap[s+3]);
    }
}

__global__ __launch_bounds__(256) void scan2_k(
    float* __restrict__ hend, const float* __restrict__ aprod, int G)
{
    int idx = blockIdx.x * 256 + threadIdx.x;
    float carry = 0.f;
    const int slab = NB * DI * DST;
    for (int g = 0; g < G; ++g) {
        size_t off = (size_t)g * slab + idx;
        float a = aprod[off];
        float e = hend[off];
        hend[off] = carry;
        carry = fmaf(a, carry, e);
    }
}

__global__ __launch_bounds__(256) void scan3_k(
    const float* __restrict__ dtf, const float* __restrict__ xs,
    const float* __restrict__ xdb, const float* __restrict__ xz,
    const float* __restrict__ A_log, const float* __restrict__ Dskip,
    const float* __restrict__ hin, __hip_bfloat16* __restrict__ y, int dir, int Cn)
{
    int d  = blockIdx.x * 256 + threadIdx.x;
    int bb = blockIdx.y;
    int g  = blockIdx.z;
    float Ad[DST], h[DST];
    size_t base = ((size_t)(g * NB + bb) * DI + d) * DST;
    #pragma unroll
    for (int s = 0; s < DST; ++s) {
        Ad[s] = -__expf(A_log[d * DST + s]);
        h[s] = hin[base + s];
    }
    float Dsk = Dskip[d];
    int i0 = g * Cn;
    for (int i = 0; i < Cn; ++i) {
        int ii = i0 + i;
        int t = dir ? (LL - 1 - ii) : ii;
        size_t m = (size_t)bb * LL + t;
        float dtv = dtf[m * DI + d];
        float xv  = xs[m * DI + d];
        const float* bc = xdb + m * XLD;
        float dtx = dtv * xv;
        float yv = 0.f;
        #pragma unroll
        for (int s = 0; s < DST; ++s) {
            float dA = __expf(dtv * Ad[s]);
            h[s] = fmaf(h[s], dA, dtx * bc[64 + s]);
            yv = fmaf(h[s], bc[80 + s], yv);
        }
        float zv = xz[m * (2 * DI) + DI + d];
        y[m * DI + d] = __float2bfloat16((yv + xv * Dsk) * siluf(zv));
    }
}

// fallback monolithic scan
__global__ __launch_bounds__(256) void scan_k(
    const float* __restrict__ dtf, const float* __restrict__ xs,
    const float* __restrict__ xdb, const float* __restrict__ xz,
    const float* __restrict__ A_log, const float* __restrict__ Dskip,
    __hip_bfloat16* __restrict__ y, int dir)
{
    int d  = blockIdx.x * 256 + threadIdx.x;
    int bb = blockIdx.y;
    float Ad[DST];
    #pragma unroll
    for (int s = 0; s < DST; ++s) Ad[s] = -__expf(A_log[d * DST + s]);
    float Dsk = Dskip[d];
    float h[DST];
    #pragma unroll
    for (int s = 0; s < DST; ++s) h[s] = 0.f;
    for (int i = 0; i < LL; ++i) {
        int t = dir ? (LL - 1 - i) : i;
        size_t m = (size_t)bb * LL + t;
        float dtv = dtf[m * DI + d];
        float xv  = xs[m * DI + d];
        const float* bc = xdb + m * XLD;
        float dtx = dtv * xv;
        float yv = 0.f;
        #pragma unroll
        for (int s = 0; s < DST; ++s) {
            float dA  = __expf(dtv * Ad[s]);
            h[s] = fmaf(h[s], dA, dtx * bc[64 + s]);
            yv = fmaf(h[s], bc[80 + s], yv);
        }
        float zv = xz[m * (2 * DI) + DI + d];
        y[m * DI + d] = __float2bfloat16((yv + xv * Dsk) * siluf(zv));
    }
}

// ---------------- Launch ----------------
extern "C" void kernel_launch(void* const* d_in, const int* in_sizes, int n_in,
                              void* d_out, int out_size, void* d_ws, size_t ws_size,
                              hipStream_t stream)
{
    const float* x      = (const float*)d_in[0];
    const float* ln_w   = (const float*)d_in[1];
    const float* ln_b   = (const float*)d_in[2];
    const float* proj_W = (const float*)d_in[21];
    const float* proj_b = (const float*)d_in[22];

    float* ws = (float*)d_ws;
    float* xz      = ws;                                 // MR*2*DI
    float* xs      = xz  + (size_t)MR * 2 * DI;          // MR*DI
    float* xdb     = xs  + (size_t)MR * DI;              // MR*XLD
    float* dtf     = xdb + (size_t)MR * XLD;             // MR*DI  (aliased: split-K partials live here first)
    float* part    = dtf;                                // KS*MR*XLD == MR*DI floats, dead before dtf written
    float* p       = dtf + (size_t)MR * DI;
    __hip_bfloat16* nb  = (__hip_bfloat16*)p; p += (size_t)MR * DM / 2;
    __hip_bfloat16* wb  = (__hip_bfloat16*)p; p += (size_t)2 * DI * DM / 2;
    __hip_bfloat16* xsb = (__hip_bfloat16*)p; p += (size_t)MR * DI / 2;
    __hip_bfloat16* wpb = (__hip_bfloat16*)p; p += (size_t)128 * DI / 2;
    __hip_bfloat16* ab  = (__hip_bfloat16*)p; p += (size_t)MR * DI / 2;
    __hip_bfloat16* cb  = (__hip_bfloat16*)p; p += (size_t)MR * 2 * DM / 2;
    __hip_bfloat16* pwb = (__hip_bfloat16*)p; p += (size_t)DM * 2 * DM / 2;
    float* hbuf = p;
    size_t base_floats = (size_t)(hbuf - ws);

    const size_t slab = (size_t)NB * DI * DST;
    int G = 64;
    while (G > 4 && (base_floats + 2 * (size_t)G * slab) * 4 > ws_size) G >>= 1;
    int useChunks = ((base_floats + 2 * (size_t)G * slab) * 4 <= ws_size);
    float* abuf = hbuf + (size_t)G * slab;
    int Cn = useChunks ? LL / G : LL;

    layernorm_k<<<MR, 256, 0, stream>>>(x, ln_w, ln_b, nb);

    for (int dir = 0; dir < 2; ++dir) {
        const float* inW    = (const float*)d_in[3 + 9 * dir + 0];
        const float* convW  = (const float*)d_in[3 + 9 * dir + 1];
        const float* convb  = (const float*)d_in[3 + 9 * dir + 2];
        const float* xprojW = (const float*)d_in[3 + 9 * dir + 3];
        const float* dtW    = (const float*)d_in[3 + 9 * dir + 4];
        const float* dtb    = (const float*)d_in[3 + 9 * dir + 5];
        const float* A_log  = (const float*)d_in[3 + 9 * dir + 6];
        const float* Dskip  = (const float*)d_in[3 + 9 * dir + 7];
        const float* outW   = (const float*)d_in[3 + 9 * dir + 8];

        // inW -> bf16 ; xz = nb @ inW^T  [MR, 2*DI] fp32
        cvt_bf16_k<<<(2 * DI * DM) / 1024, 256, 0, stream>>>(inW, wb);
        gemm_mfma<0><<<dim3((2 * DI) / 128, MR / 128), 256, 0, stream>>>(
            nb, DM, wb, DM, xz, 2 * DI, DM, nullptr, nullptr, 0);

        // xs (+bf16 copy) = silu(depthwise_conv(xz[:, :DI]))
        conv_silu_k<<<(MR * DI) / 256, 256, 0, stream>>>(xz, convW, convb, xs, xsb, dir);

        // x-proj: split-K MFMA partials then reduce -> xdb [MR, XLD]
        cvt_pad96_k<<<(128 * DI) / 1024, 256, 0, stream>>>(xprojW, wpb);
        xproj_part_k<<<dim3(KS, MR / 128), 256, 0, stream>>>(xsb, wpb, part);
        xproj_reduce_k<<<(MR * XLD) / 1024, 256, 0, stream>>>(part, xdb);

        // dtf = softplus(xdb[:, :64] @ dtW^T + dtb)  [MR, DI] fp32 (overwrites part)
        gemm_abt<1><<<dim3(DI / 64, MR / 64), 256, 0, stream>>>(
            xdb, XLD, dtW, DTR, dtf, DI, DI, DTR, dtb);

        // selective scan -> ab (bf16)
        if (useChunks) {
            scan1_k<<<dim3(DI / 256, NB, G), 256, 0, stream>>>(
                dtf, xs, xdb, A_log, hbuf, abuf, dir, Cn);
            scan2_k<<<(NB * DI * DST) / 256, 256, 0, stream>>>(hbuf, abuf, G);
            scan3_k<<<dim3(DI / 256, NB, G), 256, 0, stream>>>(
                dtf, xs, xdb, xz, A_log, Dskip, hbuf, ab, dir, Cn);
        } else {
            scan_k<<<dim3(DI / 256, NB), 256, 0, stream>>>(
                dtf, xs, xdb, xz, A_log, Dskip, ab, dir);
        }

        // outW -> bf16 ; comb[:, dir*DM:+DM] = ab @ outW^T (bf16 store)
        cvt_bf16_k<<<(DM * DI) / 1024, 256, 0, stream>>>(outW, wb);
        gemm_mfma<1><<<dim3(DM / 128, MR / 128), 256, 0, stream>>>(
            ab, DI, wb, DI, cb + dir * DM, 2 * DM, DI, nullptr, nullptr, 0);
    }

    // final: out = x + cb @ proj_W^T + proj_b  (fp32 out)
    cvt_bf16_k<<<(DM * 2 * DM) / 1024, 256, 0, stream>>>(proj_W, pwb);
    gemm_mfma<2><<<dim3(DM / 128, MR / 128), 256, 0, stream>>>(
        cb, 2 * DM, pwb, 2 * DM, (float*)d_out, DM, 2 * DM, proj_b, x, DM);
}

// Round 5
// 452.466 us; speedup vs baseline: 5.4634x; 1.4121x over previous
//
#include <hip/hip_runtime.h>
#include <hip/hip_bf16.h>
#include <math.h>

#define DM   1024   // d_model
#define DI   2048   // d_inner
#define DTR  64     // dt_rank
#define DST  16     // d_state
#define NB   2      // batch
#define LL   1024   // seq len
#define MR   (NB*LL)  // 2048 rows
#define XLD  128    // xdb padded leading dim
#define KS   8      // split-K factor for x-proj (K slices of 256)

typedef __bf16 bf16x8 __attribute__((ext_vector_type(8)));
typedef float  f32x4  __attribute__((ext_vector_type(4)));

__device__ __forceinline__ float siluf(float x) { return x / (1.f + __expf(-x)); }
__device__ __forceinline__ float softplusf(float x) {
    return fmaxf(x, 0.f) + log1pf(__expf(-fabsf(x)));
}
__device__ __forceinline__ unsigned short f2bf(float f) {
    __hip_bfloat16 h = __float2bfloat16(f);
    return *reinterpret_cast<unsigned short*>(&h);
}
__device__ __forceinline__ float bf2f(__hip_bfloat16 h) { return __bfloat162float(h); }

// async global->LDS 16B: data lands at lds + lane*16 bytes (wave-uniform base).
__device__ __forceinline__ void gl2lds16(const __hip_bfloat16* g, __hip_bfloat16* l)
{
    __builtin_amdgcn_global_load_lds(
        (const __attribute__((address_space(1))) unsigned int*)g,
        (__attribute__((address_space(3))) unsigned int*)l, 16, 0, 0);
}

// ---------------- LayerNorm -> bf16 ----------------
__global__ __launch_bounds__(256) void layernorm_k(
    const float* __restrict__ x, const float* __restrict__ w,
    const float* __restrict__ b, __hip_bfloat16* __restrict__ out)
{
    int row = blockIdx.x;
    int tid = threadIdx.x;
    const float* xr = x + (size_t)row * DM;
    float4 v = *(const float4*)(xr + tid * 4);
    float s = v.x + v.y + v.z + v.w;
    float q = v.x*v.x + v.y*v.y + v.z*v.z + v.w*v.w;
    #pragma unroll
    for (int off = 32; off > 0; off >>= 1) {
        s += __shfl_xor(s, off, 64);
        q += __shfl_xor(q, off, 64);
    }
    __shared__ float ss[4], qq[4];
    int wv = tid >> 6;
    if ((tid & 63) == 0) { ss[wv] = s; qq[wv] = q; }
    __syncthreads();
    s = ss[0] + ss[1] + ss[2] + ss[3];
    q = qq[0] + qq[1] + qq[2] + qq[3];
    float mu  = s * (1.f / DM);
    float var = q * (1.f / DM) - mu * mu;
    float rstd = rsqrtf(var + 1e-5f);
    float4 wv4 = *(const float4*)(w + tid * 4);
    float4 bv4 = *(const float4*)(b + tid * 4);
    ushort4 o;
    o.x = f2bf((v.x - mu) * rstd * wv4.x + bv4.x);
    o.y = f2bf((v.y - mu) * rstd * wv4.y + bv4.y);
    o.z = f2bf((v.z - mu) * rstd * wv4.z + bv4.z);
    o.w = f2bf((v.w - mu) * rstd * wv4.w + bv4.w);
    *(ushort4*)((unsigned short*)out + (size_t)row * DM + tid * 4) = o;
}

// ---------------- one-shot fp32->bf16 of all plain weights ----------------
// warena layout (bf16): [f_inW 4194304][b_inW 4194304][f_outW 2097152]
//                       [b_outW 2097152][proj_W 2097152]  = 14680064
__global__ __launch_bounds__(256) void cvt_all_k(
    const float* __restrict__ s0, const float* __restrict__ s1,
    const float* __restrict__ s2, const float* __restrict__ s3,
    const float* __restrict__ s4, __hip_bfloat16* __restrict__ dst)
{
    long idx = (long)(blockIdx.x * 256 + threadIdx.x) * 4;
    const float* src; long off;
    if      (idx <  4194304L) { src = s0; off = idx; }
    else if (idx <  8388608L) { src = s1; off = idx -  4194304L; }
    else if (idx < 10485760L) { src = s2; off = idx -  8388608L; }
    else if (idx < 12582912L) { src = s3; off = idx - 10485760L; }
    else                      { src = s4; off = idx - 12582912L; }
    float4 v = *(const float4*)(src + off);
    ushort4 o;
    o.x = f2bf(v.x); o.y = f2bf(v.y); o.z = f2bf(v.z); o.w = f2bf(v.w);
    *(ushort4*)((unsigned short*)dst + idx) = o;
}

// ---------------- xprojW (96x2048) -> bf16 padded to 128 rows, both dirs ----------------
__global__ __launch_bounds__(256) void cvt_pad96_k(
    const float* __restrict__ f_in, const float* __restrict__ b_in,
    __hip_bfloat16* __restrict__ out)
{
    int z = blockIdx.y;
    const float* in = z ? b_in : f_in;
    int idx = (blockIdx.x * 256 + threadIdx.x) * 4;   // over 128*DI
    int row = idx >> 11;
    ushort4 o = make_ushort4(0, 0, 0, 0);
    if (row < 96) {
        float4 v = *(const float4*)(in + idx);
        o.x = f2bf(v.x); o.y = f2bf(v.y); o.z = f2bf(v.z); o.w = f2bf(v.w);
    }
    *(ushort4*)((unsigned short*)out + (size_t)z * 128 * DI + idx) = o;
}

// ---------------- bf16 MFMA GEMM with global_load_lds staging ----------------
// C[m,n] = sum_k A[m,k]*B[n,k].  128x128 tile, BK=64, 256 thr (4 waves x 64x64).
// LDS: 128 rows x 64 bf16 (128 B), XOR-swizzled: 16B chunk c of row r stored at
// slot c^(r&7).  Staged via per-lane-permuted global addresses (coalesced: same
// cachelines).  Fragment ds_read_b128 -> 2-way bank aliasing only (free).
// Grouped over blockIdx.z via astride/bstride/cstride (element strides).
// EPI: 1 = bf16 store, 2 = fp32 + bias[n] + res[m,n] store.
template<int EPI>
__global__ __launch_bounds__(256) void gemm_gl(
    const __hip_bfloat16* __restrict__ A, int lda, size_t astride,
    const __hip_bfloat16* __restrict__ B, int ldb, size_t bstride,
    void* __restrict__ Cp, int ldc, size_t cstride, int K,
    const float* __restrict__ bias,
    const float* __restrict__ res, int ldres)
{
    __shared__ __hip_bfloat16 As[128 * 64];
    __shared__ __hip_bfloat16 Bs[128 * 64];
    const int tid  = threadIdx.x;
    const int z    = blockIdx.z;
    const int bm   = blockIdx.y * 128;
    const int bn   = blockIdx.x * 128;
    const __hip_bfloat16* Az = A + (size_t)z * astride;
    const __hip_bfloat16* Bz = B + (size_t)z * bstride;
    const int wv   = tid >> 6;
    const int lane = tid & 63;
    const int wr   = (wv >> 1) * 64;
    const int wc   = (wv & 1) * 64;
    // staging: wave wv rows [wv*32, wv*32+32), 4 insts x (8 rows x 8 chunks)
    const int srow = wv * 32 + (lane >> 3);
    const int cg   = ((lane & 7) ^ (lane >> 3)) * 8;   // swizzled global chunk (elements)
    // fragments
    const int fr   = lane & 15;
    const int quad = lane >> 4;
    const int pc0  = (quad ^ (fr & 7)) * 8;            // phys chunk, kk=0 (elements)
    const int pc1  = ((4 + quad) ^ (fr & 7)) * 8;      // phys chunk, kk=1

    f32x4 acc[4][4] = {};

    for (int k0 = 0; k0 < K; k0 += 64) {
        __syncthreads();
        #pragma unroll
        for (int i = 0; i < 4; ++i) {
            int r = srow + i * 8;
            gl2lds16(Az + (size_t)(bm + r) * lda + k0 + cg, As + wv * 2048 + i * 512);
            gl2lds16(Bz + (size_t)(bn + r) * ldb + k0 + cg, Bs + wv * 2048 + i * 512);
        }
        __syncthreads();
        #pragma unroll
        for (int kk = 0; kk < 2; ++kk) {
            const int pc = kk ? pc1 : pc0;
            bf16x8 af[4], bf_[4];
            #pragma unroll
            for (int i = 0; i < 4; ++i) {
                af[i]  = *(const bf16x8*)(As + (wr + i * 16 + fr) * 64 + pc);
                bf_[i] = *(const bf16x8*)(Bs + (wc + i * 16 + fr) * 64 + pc);
            }
            #pragma unroll
            for (int i = 0; i < 4; ++i)
                #pragma unroll
                for (int j = 0; j < 4; ++j)
                    acc[i][j] = __builtin_amdgcn_mfma_f32_16x16x32_bf16(
                        af[i], bf_[j], acc[i][j], 0, 0, 0);
        }
    }

    const int er = quad * 4;           // C/D: row = quad*4+reg, col = lane&15
    const int ec = fr;
    #pragma unroll
    for (int i = 0; i < 4; ++i) {
        #pragma unroll
        for (int j = 0; j < 4; ++j) {
            int row = bm + wr + i * 16 + er;
            int col = bn + wc + j * 16 + ec;
            #pragma unroll
            for (int r = 0; r < 4; ++r) {
                float v = acc[i][j][r];
                if (EPI == 1) {
                    ((__hip_bfloat16*)Cp)[(size_t)z * cstride +
                        (size_t)(row + r) * ldc + col] = __float2bfloat16(v);
                } else {
                    ((float*)Cp)[(size_t)(row + r) * ldc + col] =
                        v + bias[col] + res[(size_t)(row + r) * ldres + col];
                }
            }
        }
    }
}

// ---------------- x-proj split-K partials, grouped over dir ----------------
// part[dir][ks][MR][XLD]; A = xs bf16 [dir][MR,DI], B = wpb [dir][128,DI].
__global__ __launch_bounds__(256) void xproj_part_k(
    const __hip_bfloat16* __restrict__ A,
    const __hip_bfloat16* __restrict__ B,
    float* __restrict__ part)
{
    __shared__ __hip_bfloat16 As[128 * 64];
    __shared__ __hip_bfloat16 Bs[128 * 64];
    const int tid  = threadIdx.x;
    const int ks   = blockIdx.x;
    const int bm   = blockIdx.y * 128;
    const int z    = blockIdx.z;
    const __hip_bfloat16* Az = A + (size_t)z * MR * DI;
    const __hip_bfloat16* Bz = B + (size_t)z * 128 * DI;
    const int kb   = ks * (DI / KS);
    const int wv   = tid >> 6;
    const int lane = tid & 63;
    const int wr   = (wv >> 1) * 64;
    const int wc   = (wv & 1) * 64;
    const int srow = wv * 32 + (lane >> 3);
    const int cg   = ((lane & 7) ^ (lane >> 3)) * 8;
    const int fr   = lane & 15;
    const int quad = lane >> 4;
    const int pc0  = (quad ^ (fr & 7)) * 8;
    const int pc1  = ((4 + quad) ^ (fr & 7)) * 8;

    f32x4 acc[4][4] = {};

    #pragma unroll
    for (int k0 = 0; k0 < DI / KS; k0 += 64) {
        __syncthreads();
        #pragma unroll
        for (int i = 0; i < 4; ++i) {
            int r = srow + i * 8;
            gl2lds16(Az + (size_t)(bm + r) * DI + kb + k0 + cg, As + wv * 2048 + i * 512);
            gl2lds16(Bz + (size_t)r * DI + kb + k0 + cg,        Bs + wv * 2048 + i * 512);
        }
        __syncthreads();
        #pragma unroll
        for (int kk = 0; kk < 2; ++kk) {
            const int pc = kk ? pc1 : pc0;
            bf16x8 af[4], bf_[4];
            #pragma unroll
            for (int i = 0; i < 4; ++i) {
                af[i]  = *(const bf16x8*)(As + (wr + i * 16 + fr) * 64 + pc);
                bf_[i] = *(const bf16x8*)(Bs + (wc + i * 16 + fr) * 64 + pc);
            }
            #pragma unroll
            for (int i = 0; i < 4; ++i)
                #pragma unroll
                for (int j = 0; j < 4; ++j)
                    acc[i][j] = __builtin_amdgcn_mfma_f32_16x16x32_bf16(
                        af[i], bf_[j], acc[i][j], 0, 0, 0);
        }
    }

    float* dst = part + ((size_t)z * KS + ks) * MR * XLD;
    const int er = quad * 4;
    const int ec = fr;
    #pragma unroll
    for (int i = 0; i < 4; ++i)
        #pragma unroll
        for (int j = 0; j < 4; ++j) {
            int row = bm + wr + i * 16 + er;
            int col = wc + j * 16 + ec;
            #pragma unroll
            for (int r = 0; r < 4; ++r)
                dst[(size_t)(row + r) * XLD + col] = acc[i][j][r];
        }
}

// ---------------- reduce split-K partials -> xdb2[dir][MR][XLD] ----------------
__global__ __launch_bounds__(256) void xproj_reduce_k(
    const float* __restrict__ part, float* __restrict__ xdb)
{
    int z = blockIdx.y;
    size_t idx = ((size_t)blockIdx.x * 256 + threadIdx.x) * 4;   // over MR*XLD
    const float* p = part + (size_t)z * KS * MR * XLD;
    float4 s = make_float4(0.f, 0.f, 0.f, 0.f);
    #pragma unroll
    for (int ks = 0; ks < KS; ++ks) {
        float4 v = *(const float4*)(p + (size_t)ks * MR * XLD + idx);
        s.x += v.x; s.y += v.y; s.z += v.z; s.w += v.w;
    }
    *(float4*)(xdb + (size_t)z * MR * XLD + idx) = s;
}

// ---------------- fp32 GEMM for dt-proj (K=64), grouped over dir ----------------
__global__ __launch_bounds__(256) void dtproj_k(
    const float* __restrict__ A, int lda, size_t astride,   // xdb2 [dir][MR][XLD]
    const float* __restrict__ B0, const float* __restrict__ B1, int ldb,
    float* __restrict__ C, int ldc, size_t cstride,
    const float* __restrict__ bias0, const float* __restrict__ bias1)
{
    const int z = blockIdx.z;
    const float* Az = A + (size_t)z * astride;
    const float* B  = z ? B1 : B0;
    const float* bias = z ? bias1 : bias0;
    float* Cz = C + (size_t)z * cstride;

    __shared__ float As[16][68];
    __shared__ float Bs[16][68];
    const int tid = threadIdx.x;
    const int bm = blockIdx.y * 64;
    const int bn = blockIdx.x * 64;
    const int lr = tid >> 2;
    const int lk = (tid & 3) << 2;
    const int tx = tid & 15;
    const int ty = tid >> 4;
    float acc[4][4] = {};

    for (int k0 = 0; k0 < DTR; k0 += 16) {
        float4 av = *(const float4*)(Az + (size_t)(bm + lr) * lda + (k0 + lk));
        float4 bv = *(const float4*)(B  + (size_t)(bn + lr) * ldb + (k0 + lk));
        As[lk+0][lr] = av.x; As[lk+1][lr] = av.y; As[lk+2][lr] = av.z; As[lk+3][lr] = av.w;
        Bs[lk+0][lr] = bv.x; Bs[lk+1][lr] = bv.y; Bs[lk+2][lr] = bv.z; Bs[lk+3][lr] = bv.w;
        __syncthreads();
        #pragma unroll
        for (int kk = 0; kk < 16; ++kk) {
            float4 a4 = *(const float4*)&As[kk][ty << 2];
            float4 b4 = *(const float4*)&Bs[kk][tx << 2];
            float a[4] = {a4.x, a4.y, a4.z, a4.w};
            float b[4] = {b4.x, b4.y, b4.z, b4.w};
            #pragma unroll
            for (int i = 0; i < 4; ++i)
                #pragma unroll
                for (int j = 0; j < 4; ++j)
                    acc[i][j] = fmaf(a[i], b[j], acc[i][j]);
        }
        __syncthreads();
    }

    #pragma unroll
    for (int i = 0; i < 4; ++i) {
        int row  = bm + (ty << 2) + i;
        int col0 = bn + (tx << 2);
        #pragma unroll
        for (int j = 0; j < 4; ++j) {
            int col = col0 + j;
            Cz[(size_t)row * ldc + col] = softplusf(acc[i][j] + bias[col]);
        }
    }
}

// ---------------- Depthwise conv (width 4) + SiLU, both dirs ----------------
// xz2: bf16 [dir][MR][2*DI]; out xsb2: bf16 [dir][MR][DI].
__global__ __launch_bounds__(256) void conv_silu_k(
    const __hip_bfloat16* __restrict__ xz2,
    const float* __restrict__ fW, const float* __restrict__ fb,
    const float* __restrict__ bW, const float* __restrict__ bb_,
    __hip_bfloat16* __restrict__ xsb2)
{
    int dirv = blockIdx.y;
    int idx = blockIdx.x * 256 + threadIdx.x;   // over MR*DI
    int d = idx & (DI - 1);
    int m = idx >> 11;
    int t = m & (LL - 1);
    int bb = m >> 10;
    const float* w  = (dirv ? bW : fW) + d * 4;
    const __hip_bfloat16* xz = xz2 + (size_t)dirv * MR * 2 * DI;
    float acc = (dirv ? bb_ : fb)[d];
    if (dirv == 0) {
        #pragma unroll
        for (int k = 0; k < 4; ++k) {
            int tt = t - 3 + k;
            if (tt >= 0)
                acc = fmaf(w[k], bf2f(xz[(size_t)(bb * LL + tt) * (2 * DI) + d]), acc);
        }
    } else {
        #pragma unroll
        for (int k = 0; k < 4; ++k) {
            int tt = t + 3 - k;
            if (tt < LL)
                acc = fmaf(w[k], bf2f(xz[(size_t)(bb * LL + tt) * (2 * DI) + d]), acc);
        }
    }
    xsb2[(size_t)dirv * MR * DI + (size_t)m * DI + d] = __float2bfloat16(siluf(acc));
}

// ---------------- Chunked selective scan, both dirs ----------------
__global__ __launch_bounds__(256) void scan1_k(
    const float* __restrict__ dtf2, const __hip_bfloat16* __restrict__ xsb2,
    const float* __restrict__ xdb2,
    const float* __restrict__ fA, const float* __restrict__ bA,
    float* __restrict__ hend, float* __restrict__ aprod, int G, int Cn)
{
    int d  = blockIdx.x * 256 + threadIdx.x;
    int bb = blockIdx.y;
    int zz = blockIdx.z;
    int dirv = (zz >= G) ? 1 : 0;
    int g = zz - (dirv ? G : 0);
    const float* A_log = dirv ? bA : fA;
    const float* dtf = dtf2 + (size_t)dirv * MR * DI;
    const __hip_bfloat16* xs = xsb2 + (size_t)dirv * MR * DI;
    const float* xdb = xdb2 + (size_t)dirv * MR * XLD;
    size_t hoff = (size_t)dirv * G * (NB * DI * DST);

    float Ad[DST], h[DST], ap[DST];
    #pragma unroll
    for (int s = 0; s < DST; ++s) {
        Ad[s] = -__expf(A_log[d * DST + s]);
        h[s] = 0.f; ap[s] = 1.f;
    }
    int i0 = g * Cn;
    for (int i = 0; i < Cn; ++i) {
        int ii = i0 + i;
        int t = dirv ? (LL - 1 - ii) : ii;
        size_t m = (size_t)bb * LL + t;
        float dtv = dtf[m * DI + d];
        float xv  = bf2f(xs[m * DI + d]);
        const float* bc = xdb + m * XLD;
        float dtx = dtv * xv;
        #pragma unroll
        for (int s = 0; s < DST; ++s) {
            float dA = __expf(dtv * Ad[s]);
            h[s] = fmaf(h[s], dA, dtx * bc[64 + s]);
            ap[s] *= dA;
        }
    }
    size_t base = hoff + ((size_t)(g * NB + bb) * DI + d) * DST;
    #pragma unroll
    for (int s = 0; s < DST; s += 4) {
        *(float4*)(hend  + base + s) = make_float4(h[s], h[s+1], h[s+2], h[s+3]);
        *(float4*)(aprod + base + s) = make_float4(ap[s], ap[s+1], ap[s+2], ap[s+3]);
    }
}

__global__ __launch_bounds__(256) void scan2_k(
    float* __restrict__ hend, const float* __restrict__ aprod, int G)
{
    int dirv = blockIdx.y;
    int idx = blockIdx.x * 256 + threadIdx.x;   // over NB*DI*DST
    const int slab = NB * DI * DST;
    size_t hoff = (size_t)dirv * G * slab;
    float carry = 0.f;
    for (int g = 0; g < G; ++g) {
        size_t off = hoff + (size_t)g * slab + idx;
        float a = aprod[off];
        float e = hend[off];
        hend[off] = carry;
        carry = fmaf(a, carry, e);
    }
}

__global__ __launch_bounds__(256) void scan3_k(
    const float* __restrict__ dtf2, __hip_bfloat16* __restrict__ xsb2,
    const float* __restrict__ xdb2, const __hip_bfloat16* __restrict__ xz2,
    const float* __restrict__ fA, const float* __restrict__ bA,
    const float* __restrict__ fD, const float* __restrict__ bD,
    const float* __restrict__ hin, int G, int Cn)
{
    int d  = blockIdx.x * 256 + threadIdx.x;
    int bb = blockIdx.y;
    int zz = blockIdx.z;
    int dirv = (zz >= G) ? 1 : 0;
    int g = zz - (dirv ? G : 0);
    const float* A_log = dirv ? bA : fA;
    const float* Dskip = dirv ? bD : fD;
    const float* dtf = dtf2 + (size_t)dirv * MR * DI;
    __hip_bfloat16* xs = xsb2 + (size_t)dirv * MR * DI;  // read xs / write y in place
    const float* xdb = xdb2 + (size_t)dirv * MR * XLD;
    const __hip_bfloat16* xz = xz2 + (size_t)dirv * MR * 2 * DI;
    size_t hoff = (size_t)dirv * G * (NB * DI * DST);

    float Ad[DST], h[DST];
    size_t base = hoff + ((size_t)(g * NB + bb) * DI + d) * DST;
    #pragma unroll
    for (int s = 0; s < DST; ++s) {
        Ad[s] = -__expf(A_log[d * DST + s]);
        h[s] = hin[base + s];
    }
    float Dsk = Dskip[d];
    int i0 = g * Cn;
    for (int i = 0; i < Cn; ++i) {
        int ii = i0 + i;
        int t = dirv ? (LL - 1 - ii) : ii;
        size_t m = (size_t)bb * LL + t;
        float dtv = dtf[m * DI + d];
        float xv  = bf2f(xs[m * DI + d]);
        const float* bc = xdb + m * XLD;
        float dtx = dtv * xv;
        float yv = 0.f;
        #pragma unroll
        for (int s = 0; s < DST; ++s) {
            float dA = __expf(dtv * Ad[s]);
            h[s] = fmaf(h[s], dA, dtx * bc[64 + s]);
            yv = fmaf(h[s], bc[80 + s], yv);
        }
        float zv = bf2f(xz[m * (2 * DI) + DI + d]);
        xs[m * DI + d] = __float2bfloat16((yv + xv * Dsk) * siluf(zv));
    }
}

// fallback monolithic scan (both dirs), only if ws too small for chunk bufs
__global__ __launch_bounds__(256) void scan_mono_k(
    const float* __restrict__ dtf2, __hip_bfloat16* __restrict__ xsb2,
    const float* __restrict__ xdb2, const __hip_bfloat16* __restrict__ xz2,
    const float* __restrict__ fA, const float* __restrict__ bA,
    const float* __restrict__ fD, const float* __restrict__ bD)
{
    int d  = blockIdx.x * 256 + threadIdx.x;
    int bb = blockIdx.y;
    int dirv = blockIdx.z;
    const float* A_log = dirv ? bA : fA;
    const float* Dskip = dirv ? bD : fD;
    const float* dtf = dtf2 + (size_t)dirv * MR * DI;
    __hip_bfloat16* xs = xsb2 + (size_t)dirv * MR * DI;
    const float* xdb = xdb2 + (size_t)dirv * MR * XLD;
    const __hip_bfloat16* xz = xz2 + (size_t)dirv * MR * 2 * DI;
    float Ad[DST], h[DST];
    #pragma unroll
    for (int s = 0; s < DST; ++s) { Ad[s] = -__expf(A_log[d * DST + s]); h[s] = 0.f; }
    float Dsk = Dskip[d];
    for (int i = 0; i < LL; ++i) {
        int t = dirv ? (LL - 1 - i) : i;
        size_t m = (size_t)bb * LL + t;
        float dtv = dtf[m * DI + d];
        float xv  = bf2f(xs[m * DI + d]);
        const float* bc = xdb + m * XLD;
        float dtx = dtv * xv;
        float yv = 0.f;
        #pragma unroll
        for (int s = 0; s < DST; ++s) {
            float dA = __expf(dtv * Ad[s]);
            h[s] = fmaf(h[s], dA, dtx * bc[64 + s]);
            yv = fmaf(h[s], bc[80 + s], yv);
        }
        float zv = bf2f(xz[m * (2 * DI) + DI + d]);
        xs[m * DI + d] = __float2bfloat16((yv + xv * Dsk) * siluf(zv));
    }
}

// ---------------- Launch ----------------
extern "C" void kernel_launch(void* const* d_in, const int* in_sizes, int n_in,
                              void* d_out, int out_size, void* d_ws, size_t ws_size,
                              hipStream_t stream)
{
    const float* x      = (const float*)d_in[0];
    const float* ln_w   = (const float*)d_in[1];
    const float* ln_b   = (const float*)d_in[2];
    const float* f_inW    = (const float*)d_in[3];
    const float* f_convW  = (const float*)d_in[4];
    const float* f_convb  = (const float*)d_in[5];
    const float* f_xprojW = (const float*)d_in[6];
    const float* f_dtW    = (const float*)d_in[7];
    const float* f_dtb    = (const float*)d_in[8];
    const float* f_A_log  = (const float*)d_in[9];
    const float* f_Dskip  = (const float*)d_in[10];
    const float* f_outW   = (const float*)d_in[11];
    const float* b_inW    = (const float*)d_in[12];
    const float* b_convW  = (const float*)d_in[13];
    const float* b_convb  = (const float*)d_in[14];
    const float* b_xprojW = (const float*)d_in[15];
    const float* b_dtW    = (const float*)d_in[16];
    const float* b_dtb    = (const float*)d_in[17];
    const float* b_A_log  = (const float*)d_in[18];
    const float* b_Dskip  = (const float*)d_in[19];
    const float* b_outW   = (const float*)d_in[20];
    const float* proj_W = (const float*)d_in[21];
    const float* proj_b = (const float*)d_in[22];

    float* ws = (float*)d_ws;
    size_t o = 0;
    __hip_bfloat16* xz2  = (__hip_bfloat16*)(ws + o); o += (size_t)2 * MR * 2 * DI / 2;  // bf16 [2][MR][2DI]
    __hip_bfloat16* xsb2 = (__hip_bfloat16*)(ws + o); o += (size_t)2 * MR * DI / 2;      // bf16 xs -> y in place
    float* xdb2 = ws + o; o += (size_t)2 * MR * XLD;                                     // fp32
    float* dtf2 = ws + o;                       // fp32 [2][MR][DI]; region aliased:
    float* part = dtf2;                         //   split-K partials (2*KS*MR*XLD fl) live first
    __hip_bfloat16* cb = (__hip_bfloat16*)dtf2; //   cb [MR][2DM] bf16 lives here after scan3
    o += (size_t)2 * MR * DI;
    __hip_bfloat16* nb = (__hip_bfloat16*)(ws + o); o += (size_t)MR * DM / 2;
    __hip_bfloat16* warena = (__hip_bfloat16*)(ws + o); o += 15204352 / 2;
    float* hbuf = ws + o;
    size_t base_floats = o;

    __hip_bfloat16* wbi  = warena;               // [2][2DI][DM]
    __hip_bfloat16* wbo  = warena + 8388608;     // [2][DM][DI]
    __hip_bfloat16* pwb  = warena + 12582912;    // [DM][2DM]
    __hip_bfloat16* wpb2 = warena + 14680064;    // [2][128][DI]

    const size_t slab = (size_t)NB * DI * DST;   // 65536
    int G = 64;
    while (G > 4 && (base_floats + 4ull * G * slab) * 4 > ws_size) G >>= 1;
    int useChunks = ((base_floats + 4ull * G * slab) * 4 <= ws_size);
    float* hend  = hbuf;
    float* aprod = hbuf + 2ull * G * slab;
    int Cn = useChunks ? LL / G : LL;

    // 1-2: weights -> bf16 (one arena)
    cvt_all_k<<<14336, 256, 0, stream>>>(f_inW, b_inW, f_outW, b_outW, proj_W, warena);
    cvt_pad96_k<<<dim3(64, 2), 256, 0, stream>>>(f_xprojW, b_xprojW, wpb2);

    // 3: layernorm
    layernorm_k<<<MR, 256, 0, stream>>>(x, ln_w, ln_b, nb);

    // 4: in-proj both dirs: xz2[dir] = nb @ inW[dir]^T  (bf16 out)
    gemm_gl<1><<<dim3((2 * DI) / 128, MR / 128, 2), 256, 0, stream>>>(
        nb, DM, 0, wbi, DM, (size_t)2 * DI * DM,
        xz2, 2 * DI, (size_t)MR * 2 * DI, DM, nullptr, nullptr, 0);

    // 5: conv + silu both dirs -> xsb2
    conv_silu_k<<<dim3((MR * DI) / 256, 2), 256, 0, stream>>>(
        xz2, f_convW, f_convb, b_convW, b_convb, xsb2);

    // 6-7: x-proj split-K + reduce -> xdb2
    xproj_part_k<<<dim3(KS, MR / 128, 2), 256, 0, stream>>>(xsb2, wpb2, part);
    xproj_reduce_k<<<dim3((MR * XLD) / 1024, 2), 256, 0, stream>>>(part, xdb2);

    // 8: dt-proj both dirs -> dtf2 (overwrites part)
    dtproj_k<<<dim3(DI / 64, MR / 64, 2), 256, 0, stream>>>(
        xdb2, XLD, (size_t)MR * XLD, f_dtW, b_dtW, DTR,
        dtf2, DI, (size_t)MR * DI, f_dtb, b_dtb);

    // 9-11: selective scan both dirs; y written in place over xsb2
    if (useChunks) {
        scan1_k<<<dim3(DI / 256, NB, 2 * G), 256, 0, stream>>>(
            dtf2, xsb2, xdb2, f_A_log, b_A_log, hend, aprod, G, Cn);
        scan2_k<<<dim3((NB * DI * DST) / 256, 2), 256, 0, stream>>>(hend, aprod, G);
        scan3_k<<<dim3(DI / 256, NB, 2 * G), 256, 0, stream>>>(
            dtf2, xsb2, xdb2, xz2, f_A_log, b_A_log, f_Dskip, b_Dskip, hend, G, Cn);
    } else {
        scan_mono_k<<<dim3(DI / 256, NB, 2), 256, 0, stream>>>(
            dtf2, xsb2, xdb2, xz2, f_A_log, b_A_log, f_Dskip, b_Dskip);
    }

    // 12: out-proj both dirs -> cb columns [dir*DM, dir*DM+DM)  (overwrites dtf2)
    gemm_gl<1><<<dim3(DM / 128, MR / 128, 2), 256, 0, stream>>>(
        xsb2, DI, (size_t)MR * DI, wbo, DI, (size_t)DM * DI,
        cb, 2 * DM, (size_t)DM, DI, nullptr, nullptr, 0);

    // 13: final: out = x + cb @ proj_W^T + proj_b  (fp32)
    gemm_gl<2><<<dim3(DM / 128, MR / 128, 1), 256, 0, stream>>>(
        cb, 2 * DM, 0, pwb, 2 * DM, 0,
        (float*)d_out, DM, 0, 2 * DM, proj_b, x, DM);
}

// Round 7
// 424.791 us; speedup vs baseline: 5.8193x; 1.0651x over previous
//
#include <hip/hip_runtime.h>
#include <hip/hip_bf16.h>
#include <math.h>

#define DM   1024   // d_model
#define DI   2048   // d_inner
#define DTR  64     // dt_rank
#define DST  16     // d_state
#define NB   2      // batch
#define LL   1024   // seq len
#define MR   (NB*LL)  // 2048 rows
#define XLD  128    // xdb padded leading dim
#define KS   8      // split-K factor for x-proj (K slices of 256)

typedef __bf16 bf16x8 __attribute__((ext_vector_type(8)));
typedef float  f32x4  __attribute__((ext_vector_type(4)));

__device__ __forceinline__ float siluf(float x) { return x / (1.f + __expf(-x)); }
__device__ __forceinline__ float softplusf(float x) {
    return fmaxf(x, 0.f) + log1pf(__expf(-fabsf(x)));
}
__device__ __forceinline__ unsigned short f2bf(float f) {
    __hip_bfloat16 h = __float2bfloat16(f);
    return *reinterpret_cast<unsigned short*>(&h);
}
__device__ __forceinline__ float bf2f(__hip_bfloat16 h) { return __bfloat162float(h); }

__device__ __forceinline__ void gl2lds16(const __hip_bfloat16* g, __hip_bfloat16* l)
{
    __builtin_amdgcn_global_load_lds(
        (const __attribute__((address_space(1))) unsigned int*)g,
        (__attribute__((address_space(3))) unsigned int*)l, 16, 0, 0);
}

// ---------------- LayerNorm -> bf16 ----------------
__global__ __launch_bounds__(256) void layernorm_k(
    const float* __restrict__ x, const float* __restrict__ w,
    const float* __restrict__ b, __hip_bfloat16* __restrict__ out)
{
    int row = blockIdx.x;
    int tid = threadIdx.x;
    const float* xr = x + (size_t)row * DM;
    float4 v = *(const float4*)(xr + tid * 4);
    float s = v.x + v.y + v.z + v.w;
    float q = v.x*v.x + v.y*v.y + v.z*v.z + v.w*v.w;
    #pragma unroll
    for (int off = 32; off > 0; off >>= 1) {
        s += __shfl_xor(s, off, 64);
        q += __shfl_xor(q, off, 64);
    }
    __shared__ float ss[4], qq[4];
    int wv = tid >> 6;
    if ((tid & 63) == 0) { ss[wv] = s; qq[wv] = q; }
    __syncthreads();
    s = ss[0] + ss[1] + ss[2] + ss[3];
    q = qq[0] + qq[1] + qq[2] + qq[3];
    float mu  = s * (1.f / DM);
    float var = q * (1.f / DM) - mu * mu;
    float rstd = rsqrtf(var + 1e-5f);
    float4 wv4 = *(const float4*)(w + tid * 4);
    float4 bv4 = *(const float4*)(b + tid * 4);
    ushort4 o;
    o.x = f2bf((v.x - mu) * rstd * wv4.x + bv4.x);
    o.y = f2bf((v.y - mu) * rstd * wv4.y + bv4.y);
    o.z = f2bf((v.z - mu) * rstd * wv4.z + bv4.z);
    o.w = f2bf((v.w - mu) * rstd * wv4.w + bv4.w);
    *(ushort4*)((unsigned short*)out + (size_t)row * DM + tid * 4) = o;
}

// ---------------- one-shot fp32->bf16 of plain weights ----------------
// arena (bf16): [f_inW 4194304][b_inW 4194304][proj_W 2097152]
//               [f_dtW 131072][b_dtW 131072]  = 10747904 elements
__global__ __launch_bounds__(256) void cvt_all_k(
    const float* __restrict__ s0, const float* __restrict__ s1,
    const float* __restrict__ s2, const float* __restrict__ s3,
    const float* __restrict__ s4, __hip_bfloat16* __restrict__ dst)
{
    long idx = (long)(blockIdx.x * 256 + threadIdx.x) * 4;
    const float* src; long off;
    if      (idx <  4194304L) { src = s0; off = idx; }
    else if (idx <  8388608L) { src = s1; off = idx -  4194304L; }
    else if (idx < 10485760L) { src = s2; off = idx -  8388608L; }
    else if (idx < 10616832L) { src = s3; off = idx - 10485760L; }
    else                      { src = s4; off = idx - 10616832L; }
    float4 v = *(const float4*)(src + off);
    ushort4 o;
    o.x = f2bf(v.x); o.y = f2bf(v.y); o.z = f2bf(v.z); o.w = f2bf(v.w);
    *(ushort4*)((unsigned short*)dst + idx) = o;
}

// ---------------- xprojW (96x2048) -> bf16 padded to 128 rows ----------------
__global__ __launch_bounds__(256) void cvt_pad96_k(
    const float* __restrict__ f_in, const float* __restrict__ b_in,
    __hip_bfloat16* __restrict__ out)
{
    int z = blockIdx.y;
    const float* in = z ? b_in : f_in;
    int idx = (blockIdx.x * 256 + threadIdx.x) * 4;   // over 128*DI
    int row = idx >> 11;
    ushort4 o = make_ushort4(0, 0, 0, 0);
    if (row < 96) {
        float4 v = *(const float4*)(in + idx);
        o.x = f2bf(v.x); o.y = f2bf(v.y); o.z = f2bf(v.z); o.w = f2bf(v.w);
    }
    *(ushort4*)((unsigned short*)out + (size_t)z * 128 * DI + idx) = o;
}

// ---------------- outW [DM][DI] fp32 -> outW^T [DI][DM] bf16, both dirs ----------------
__global__ __launch_bounds__(256) void transpose_k(
    const float* __restrict__ f_o, const float* __restrict__ b_o,
    __hip_bfloat16* __restrict__ wot)
{
    int z = blockIdx.z;
    const float* src = z ? b_o : f_o;
    int c0 = blockIdx.x * 64;   // col in src (DI dim)
    int r0 = blockIdx.y * 64;   // row in src (DM dim)
    __shared__ float t[64][65];
    int tc = threadIdx.x & 63;
    int tr = threadIdx.x >> 6;
    #pragma unroll
    for (int ii = 0; ii < 16; ++ii) {
        int rl = tr + ii * 4;
        t[tc][rl] = src[(size_t)(r0 + rl) * DI + c0 + tc];
    }
    __syncthreads();
    __hip_bfloat16* dst = wot + (size_t)z * DI * DM;
    #pragma unroll
    for (int ii = 0; ii < 16; ++ii) {
        int cl = tr + ii * 4;
        dst[(size_t)(c0 + cl) * DM + r0 + tc] = __float2bfloat16(t[cl][tc]);
    }
}

// ---------------- bf16 MFMA GEMM with global_load_lds staging ----------------
// C[m,n] = sum_k A[m,k]*B[n,k]. 128x128 tile, BK=64, 256 thr (4 waves x 64x64).
// XOR-swizzled LDS (16B chunk c of row r at slot c^(r&7)); zero bank conflicts.
// z-grouped via element offsets aofs/bofs/cofs.
// EPI: 0 = fp32 store, 1 = bf16 store, 3 = softplus(v+bias_z[n]) bf16 store.
template<int EPI>
__global__ __launch_bounds__(256) void gemm_gl(
    const __hip_bfloat16* __restrict__ A, int lda, size_t aofs,
    const __hip_bfloat16* __restrict__ B, int ldb, size_t bofs,
    void* __restrict__ Cp, int ldc, size_t cofs, int K,
    const float* __restrict__ bias0, const float* __restrict__ bias1)
{
    __shared__ __hip_bfloat16 As[128 * 64];
    __shared__ __hip_bfloat16 Bs[128 * 64];
    const int tid  = threadIdx.x;
    const int z    = blockIdx.z;
    const int bm   = blockIdx.y * 128;
    const int bn   = blockIdx.x * 128;
    const __hip_bfloat16* Az = A + (size_t)z * aofs;
    const __hip_bfloat16* Bz = B + (size_t)z * bofs;
    const int wv   = tid >> 6;
    const int lane = tid & 63;
    const int wr   = (wv >> 1) * 64;
    const int wc   = (wv & 1) * 64;
    const int srow = wv * 32 + (lane >> 3);
    const int cg   = ((lane & 7) ^ (lane >> 3)) * 8;
    const int fr   = lane & 15;
    const int quad = lane >> 4;
    const int pc0  = (quad ^ (fr & 7)) * 8;
    const int pc1  = ((4 + quad) ^ (fr & 7)) * 8;

    f32x4 acc[4][4] = {};

    for (int k0 = 0; k0 < K; k0 += 64) {
        __syncthreads();
        #pragma unroll
        for (int i = 0; i < 4; ++i) {
            int r = srow + i * 8;
            gl2lds16(Az + (size_t)(bm + r) * lda + k0 + cg, As + wv * 2048 + i * 512);
            gl2lds16(Bz + (size_t)(bn + r) * ldb + k0 + cg, Bs + wv * 2048 + i * 512);
        }
        __syncthreads();
        #pragma unroll
        for (int kk = 0; kk < 2; ++kk) {
            const int pc = kk ? pc1 : pc0;
            bf16x8 af[4], bf_[4];
            #pragma unroll
            for (int i = 0; i < 4; ++i) {
                af[i]  = *(const bf16x8*)(As + (wr + i * 16 + fr) * 64 + pc);
                bf_[i] = *(const bf16x8*)(Bs + (wc + i * 16 + fr) * 64 + pc);
            }
            #pragma unroll
            for (int i = 0; i < 4; ++i)
                #pragma unroll
                for (int j = 0; j < 4; ++j)
                    acc[i][j] = __builtin_amdgcn_mfma_f32_16x16x32_bf16(
                        af[i], bf_[j], acc[i][j], 0, 0, 0);
        }
    }

    const float* bias = (EPI == 3) ? (z ? bias1 : bias0) : nullptr;
    const int er = quad * 4;
    const int ec = fr;
    #pragma unroll
    for (int i = 0; i < 4; ++i) {
        #pragma unroll
        for (int j = 0; j < 4; ++j) {
            int row = bm + wr + i * 16 + er;
            int col = bn + wc + j * 16 + ec;
            #pragma unroll
            for (int r = 0; r < 4; ++r) {
                float v = acc[i][j][r];
                if (EPI == 1) {
                    ((__hip_bfloat16*)Cp)[(size_t)z * cofs +
                        (size_t)(row + r) * ldc + col] = __float2bfloat16(v);
                } else if (EPI == 3) {
                    ((__hip_bfloat16*)Cp)[(size_t)z * cofs +
                        (size_t)(row + r) * ldc + col] =
                        __float2bfloat16(softplusf(v + bias[col]));
                } else {
                    ((float*)Cp)[(size_t)z * cofs + (size_t)(row + r) * ldc + col] = v;
                }
            }
        }
    }
}

// ---------------- x-proj split-K partials, grouped over dir ----------------
__global__ __launch_bounds__(256) void xproj_part_k(
    const __hip_bfloat16* __restrict__ A,
    const __hip_bfloat16* __restrict__ B,
    float* __restrict__ part)
{
    __shared__ __hip_bfloat16 As[128 * 64];
    __shared__ __hip_bfloat16 Bs[128 * 64];
    const int tid  = threadIdx.x;
    const int ks   = blockIdx.x;
    const int bm   = blockIdx.y * 128;
    const int z    = blockIdx.z;
    const __hip_bfloat16* Az = A + (size_t)z * MR * DI;
    const __hip_bfloat16* Bz = B + (size_t)z * 128 * DI;
    const int kb   = ks * (DI / KS);
    const int wv   = tid >> 6;
    const int lane = tid & 63;
    const int wr   = (wv >> 1) * 64;
    const int wc   = (wv & 1) * 64;
    const int srow = wv * 32 + (lane >> 3);
    const int cg   = ((lane & 7) ^ (lane >> 3)) * 8;
    const int fr   = lane & 15;
    const int quad = lane >> 4;
    const int pc0  = (quad ^ (fr & 7)) * 8;
    const int pc1  = ((4 + quad) ^ (fr & 7)) * 8;

    f32x4 acc[4][4] = {};

    #pragma unroll
    for (int k0 = 0; k0 < DI / KS; k0 += 64) {
        __syncthreads();
        #pragma unroll
        for (int i = 0; i < 4; ++i) {
            int r = srow + i * 8;
            gl2lds16(Az + (size_t)(bm + r) * DI + kb + k0 + cg, As + wv * 2048 + i * 512);
            gl2lds16(Bz + (size_t)r * DI + kb + k0 + cg,        Bs + wv * 2048 + i * 512);
        }
        __syncthreads();
        #pragma unroll
        for (int kk = 0; kk < 2; ++kk) {
            const int pc = kk ? pc1 : pc0;
            bf16x8 af[4], bf_[4];
            #pragma unroll
            for (int i = 0; i < 4; ++i) {
                af[i]  = *(const bf16x8*)(As + (wr + i * 16 + fr) * 64 + pc);
                bf_[i] = *(const bf16x8*)(Bs + (wc + i * 16 + fr) * 64 + pc);
            }
            #pragma unroll
            for (int i = 0; i < 4; ++i)
                #pragma unroll
                for (int j = 0; j < 4; ++j)
                    acc[i][j] = __builtin_amdgcn_mfma_f32_16x16x32_bf16(
                        af[i], bf_[j], acc[i][j], 0, 0, 0);
        }
    }

    float* dst = part + ((size_t)z * KS + ks) * MR * XLD;
    const int er = quad * 4;
    const int ec = fr;
    #pragma unroll
    for (int i = 0; i < 4; ++i)
        #pragma unroll
        for (int j = 0; j < 4; ++j) {
            int row = bm + wr + i * 16 + er;
            int col = wc + j * 16 + ec;
            #pragma unroll
            for (int r = 0; r < 4; ++r)
                dst[(size_t)(row + r) * XLD + col] = acc[i][j][r];
        }
}

// ---------------- reduce x-proj partials -> xdb2 fp32 + dt-cols bf16 ----------------
__global__ __launch_bounds__(256) void xproj_reduce_k(
    const float* __restrict__ part, float* __restrict__ xdb,
    __hip_bfloat16* __restrict__ xdbt)
{
    int z = blockIdx.y;
    size_t idx = ((size_t)blockIdx.x * 256 + threadIdx.x) * 4;   // over MR*XLD
    const float* p = part + (size_t)z * KS * MR * XLD;
    float4 s = make_float4(0.f, 0.f, 0.f, 0.f);
    #pragma unroll
    for (int ks = 0; ks < KS; ++ks) {
        float4 v = *(const float4*)(p + (size_t)ks * MR * XLD + idx);
        s.x += v.x; s.y += v.y; s.z += v.z; s.w += v.w;
    }
    *(float4*)(xdb + (size_t)z * MR * XLD + idx) = s;
    int c = (int)(idx & (XLD - 1));
    if (c < 64) {
        size_t m = idx >> 7;
        ushort4 o;
        o.x = f2bf(s.x); o.y = f2bf(s.y); o.z = f2bf(s.z); o.w = f2bf(s.w);
        *(ushort4*)((unsigned short*)xdbt + (size_t)z * MR * 64 + m * 64 + c) = o;
    }
}

// ---------------- Depthwise conv (width 4) + SiLU, both dirs ----------------
__global__ __launch_bounds__(256) void conv_silu_k(
    const __hip_bfloat16* __restrict__ xz2,
    const float* __restrict__ fW, const float* __restrict__ fb,
    const float* __restrict__ bW, const float* __restrict__ bb_,
    __hip_bfloat16* __restrict__ xsb2)
{
    int dirv = blockIdx.y;
    int idx = blockIdx.x * 256 + threadIdx.x;   // over MR*DI
    int d = idx & (DI - 1);
    int m = idx >> 11;
    int t = m & (LL - 1);
    int bb = m >> 10;
    const float* w  = (dirv ? bW : fW) + d * 4;
    const __hip_bfloat16* xz = xz2 + (size_t)dirv * MR * 2 * DI;
    float acc = (dirv ? bb_ : fb)[d];
    if (dirv == 0) {
        #pragma unroll
        for (int k = 0; k < 4; ++k) {
            int tt = t - 3 + k;
            if (tt >= 0)
                acc = fmaf(w[k], bf2f(xz[(size_t)(bb * LL + tt) * (2 * DI) + d]), acc);
        }
    } else {
        #pragma unroll
        for (int k = 0; k < 4; ++k) {
            int tt = t + 3 - k;
            if (tt < LL)
                acc = fmaf(w[k], bf2f(xz[(size_t)(bb * LL + tt) * (2 * DI) + d]), acc);
        }
    }
    xsb2[(size_t)dirv * MR * DI + (size_t)m * DI + d] = __float2bfloat16(siluf(acc));
}

// ---------------- Chunked selective scan, both dirs ----------------
// A_log is structurally log(tile(arange(1..17))) -> A_s = -(s+1); power form
// dA_s = r^(s+1), r = exp(-dt), guarded per-thread; exact path otherwise.
__global__ __launch_bounds__(256) void scan1_k(
    const __hip_bfloat16* __restrict__ dtf2, const __hip_bfloat16* __restrict__ xsb2,
    const float* __restrict__ xdb2,
    const float* __restrict__ fA, const float* __restrict__ bA,
    float* __restrict__ hend, float* __restrict__ aprod, int G, int Cn)
{
    int d  = blockIdx.x * 256 + threadIdx.x;
    int bb = blockIdx.y;
    int zz = blockIdx.z;
    int dirv = (zz >= G) ? 1 : 0;
    int g = zz - (dirv ? G : 0);
    const float* A_log = dirv ? bA : fA;
    const __hip_bfloat16* dtf = dtf2 + (size_t)dirv * MR * DI;
    const __hip_bfloat16* xs = xsb2 + (size_t)dirv * MR * DI;
    const float* xdb = xdb2 + (size_t)dirv * MR * XLD;
    size_t hoff = (size_t)dirv * G * (NB * DI * DST);

    float Ad[DST], h[DST], ap[DST];
    bool pw = true;
    #pragma unroll
    for (int s = 0; s < DST; ++s) {
        Ad[s] = -__expf(A_log[d * DST + s]);
        pw = pw && (fabsf(Ad[s] + (float)(s + 1)) < 1e-3f * (s + 1));
        h[s] = 0.f; ap[s] = 1.f;
    }
    int i0 = g * Cn;
    for (int i = 0; i < Cn; ++i) {
        int ii = i0 + i;
        int t = dirv ? (LL - 1 - ii) : ii;
        size_t m = (size_t)bb * LL + t;
        float dtv = bf2f(dtf[m * DI + d]);
        float xv  = bf2f(xs[m * DI + d]);
        const float* bc = xdb + m * XLD;
        float dtx = dtv * xv;
        float dAv[DST];
        if (pw) {
            float r = __expf(-dtv);
            float a = r;
            #pragma unroll
            for (int s = 0; s < DST; ++s) { dAv[s] = a; a *= r; }
        } else {
            #pragma unroll
            for (int s = 0; s < DST; ++s) dAv[s] = __expf(dtv * Ad[s]);
        }
        #pragma unroll
        for (int s = 0; s < DST; ++s) {
            h[s] = fmaf(h[s], dAv[s], dtx * bc[64 + s]);
            ap[s] *= dAv[s];
        }
    }
    size_t base = hoff + ((size_t)(g * NB + bb) * DI + d) * DST;
    #pragma unroll
    for (int s = 0; s < DST; s += 4) {
        *(float4*)(hend  + base + s) = make_float4(h[s], h[s+1], h[s+2], h[s+3]);
        *(float4*)(aprod + base + s) = make_float4(ap[s], ap[s+1], ap[s+2], ap[s+3]);
    }
}

__global__ __launch_bounds__(256) void scan2_k(
    float* __restrict__ hend, const float* __restrict__ aprod, int G)
{
    int dirv = blockIdx.y;
    int idx = blockIdx.x * 256 + threadIdx.x;   // over NB*DI*DST
    const int slab = NB * DI * DST;
    size_t hoff = (size_t)dirv * G * slab;
    float carry = 0.f;
    for (int g = 0; g < G; ++g) {
        size_t off = hoff + (size_t)g * slab + idx;
        float a = aprod[off];
        float e = hend[off];
        hend[off] = carry;
        carry = fmaf(a, carry, e);
    }
}

__global__ __launch_bounds__(256) void scan3_k(
    const __hip_bfloat16* __restrict__ dtf2, const __hip_bfloat16* __restrict__ xsb2,
    const float* __restrict__ xdb2, const __hip_bfloat16* __restrict__ xz2,
    const float* __restrict__ fA, const float* __restrict__ bA,
    const float* __restrict__ fD, const float* __restrict__ bD,
    const float* __restrict__ hin, __hip_bfloat16* __restrict__ ycat, int G, int Cn)
{
    int d  = blockIdx.x * 256 + threadIdx.x;
    int bb = blockIdx.y;
    int zz = blockIdx.z;
    int dirv = (zz >= G) ? 1 : 0;
    int g = zz - (dirv ? G : 0);
    const float* A_log = dirv ? bA : fA;
    const float* Dskip = dirv ? bD : fD;
    const __hip_bfloat16* dtf = dtf2 + (size_t)dirv * MR * DI;
    const __hip_bfloat16* xs = xsb2 + (size_t)dirv * MR * DI;
    const float* xdb = xdb2 + (size_t)dirv * MR * XLD;
    const __hip_bfloat16* xz = xz2 + (size_t)dirv * MR * 2 * DI;
    size_t hoff = (size_t)dirv * G * (NB * DI * DST);

    float Ad[DST], h[DST];
    bool pw = true;
    size_t base = hoff + ((size_t)(g * NB + bb) * DI + d) * DST;
    #pragma unroll
    for (int s = 0; s < DST; ++s) {
        Ad[s] = -__expf(A_log[d * DST + s]);
        pw = pw && (fabsf(Ad[s] + (float)(s + 1)) < 1e-3f * (s + 1));
        h[s] = hin[base + s];
    }
    float Dsk = Dskip[d];
    int i0 = g * Cn;
    for (int i = 0; i < Cn; ++i) {
        int ii = i0 + i;
        int t = dirv ? (LL - 1 - ii) : ii;
        size_t m = (size_t)bb * LL + t;
        float dtv = bf2f(dtf[m * DI + d]);
        float xv  = bf2f(xs[m * DI + d]);
        const float* bc = xdb + m * XLD;
        float dtx = dtv * xv;
        float dAv[DST];
        if (pw) {
            float r = __expf(-dtv);
            float a = r;
            #pragma unroll
            for (int s = 0; s < DST; ++s) { dAv[s] = a; a *= r; }
        } else {
            #pragma unroll
            for (int s = 0; s < DST; ++s) dAv[s] = __expf(dtv * Ad[s]);
        }
        float yv = 0.f;
        #pragma unroll
        for (int s = 0; s < DST; ++s) {
            h[s] = fmaf(h[s], dAv[s], dtx * bc[64 + s]);
            yv = fmaf(h[s], bc[80 + s], yv);
        }
        float zv = bf2f(xz[m * (2 * DI) + DI + d]);
        ycat[m * (2 * DI) + (size_t)dirv * DI + d] =
            __float2bfloat16((yv + xv * Dsk) * siluf(zv));
    }
}

// fallback monolithic scan (both dirs) if ws too small for chunk bufs
__global__ __launch_bounds__(256) void scan_mono_k(
    const __hip_bfloat16* __restrict__ dtf2, const __hip_bfloat16* __restrict__ xsb2,
    const float* __restrict__ xdb2, const __hip_bfloat16* __restrict__ xz2,
    const float* __restrict__ fA, const float* __restrict__ bA,
    const float* __restrict__ fD, const float* __restrict__ bD,
    __hip_bfloat16* __restrict__ ycat)
{
    int d  = blockIdx.x * 256 + threadIdx.x;
    int bb = blockIdx.y;
    int dirv = blockIdx.z;
    const float* A_log = dirv ? bA : fA;
    const float* Dskip = dirv ? bD : fD;
    const __hip_bfloat16* dtf = dtf2 + (size_t)dirv * MR * DI;
    const __hip_bfloat16* xs = xsb2 + (size_t)dirv * MR * DI;
    const float* xdb = xdb2 + (size_t)dirv * MR * XLD;
    const __hip_bfloat16* xz = xz2 + (size_t)dirv * MR * 2 * DI;
    float Ad[DST], h[DST];
    #pragma unroll
    for (int s = 0; s < DST; ++s) { Ad[s] = -__expf(A_log[d * DST + s]); h[s] = 0.f; }
    float Dsk = Dskip[d];
    for (int i = 0; i < LL; ++i) {
        int t = dirv ? (LL - 1 - i) : i;
        size_t m = (size_t)bb * LL + t;
        float dtv = bf2f(dtf[m * DI + d]);
        float xv  = bf2f(xs[m * DI + d]);
        const float* bc = xdb + m * XLD;
        float dtx = dtv * xv;
        float yv = 0.f;
        #pragma unroll
        for (int s = 0; s < DST; ++s) {
            float dA = __expf(dtv * Ad[s]);
            h[s] = fmaf(h[s], dA, dtx * bc[64 + s]);
            yv = fmaf(h[s], bc[80 + s], yv);
        }
        float zv = bf2f(xz[m * (2 * DI) + DI + d]);
        ycat[m * (2 * DI) + (size_t)dirv * DI + d] =
            __float2bfloat16((yv + xv * Dsk) * siluf(zv));
    }
}

// ---------------- final reduce: out = x + proj_b + sum_z part[z] ----------------
__global__ __launch_bounds__(256) void final_reduce_k(
    const float* __restrict__ part, const float* __restrict__ x,
    const float* __restrict__ proj_b, float* __restrict__ out)
{
    size_t idx = ((size_t)blockIdx.x * 256 + threadIdx.x) * 4;   // over MR*DM
    float4 s = make_float4(0.f, 0.f, 0.f, 0.f);
    #pragma unroll
    for (int z = 0; z < 4; ++z) {
        float4 v = *(const float4*)(part + (size_t)z * MR * DM + idx);
        s.x += v.x; s.y += v.y; s.z += v.z; s.w += v.w;
    }
    float4 xv = *(const float4*)(x + idx);
    int col = (int)(idx & (DM - 1));
    float4 pb = *(const float4*)(proj_b + col);
    float4 o;
    o.x = xv.x + pb.x + s.x;
    o.y = xv.y + pb.y + s.y;
    o.z = xv.z + pb.z + s.z;
    o.w = xv.w + pb.w + s.w;
    *(float4*)(out + idx) = o;
}

// ---------------- Launch ----------------
extern "C" void kernel_launch(void* const* d_in, const int* in_sizes, int n_in,
                              void* d_out, int out_size, void* d_ws, size_t ws_size,
                              hipStream_t stream)
{
    const float* x      = (const float*)d_in[0];
    const float* ln_w   = (const float*)d_in[1];
    const float* ln_b   = (const float*)d_in[2];
    const float* f_inW    = (const float*)d_in[3];
    const float* f_convW  = (const float*)d_in[4];
    const float* f_convb  = (const float*)d_in[5];
    const float* f_xprojW = (const float*)d_in[6];
    const float* f_dtW    = (const float*)d_in[7];
    const float* f_dtb    = (const float*)d_in[8];
    const float* f_A_log  = (const float*)d_in[9];
    const float* f_Dskip  = (const float*)d_in[10];
    const float* f_outW   = (const float*)d_in[11];
    const float* b_inW    = (const float*)d_in[12];
    const float* b_convW  = (const float*)d_in[13];
    const float* b_convb  = (const float*)d_in[14];
    const float* b_xprojW = (const float*)d_in[15];
    const float* b_dtW    = (const float*)d_in[16];
    const float* b_dtb    = (const float*)d_in[17];
    const float* b_A_log  = (const float*)d_in[18];
    const float* b_Dskip  = (const float*)d_in[19];
    const float* b_outW   = (const float*)d_in[20];
    const float* proj_W = (const float*)d_in[21];
    const float* proj_b = (const float*)d_in[22];

    float* ws = (float*)d_ws;
    size_t o = 0;
    // xz2 region (8,388,608 floats): holds wot [2][DI][DM] bf16 during weight
    // prep (dead once Wcat GEMM finishes), then xz2 bf16 [2][MR][2DI], then
    // the final split-K fp32 partials [4][MR][DM] (xz2 dead after scan3).
    __hip_bfloat16* xz2  = (__hip_bfloat16*)(ws + o);
    __hip_bfloat16* wot  = xz2;
    float* fpart = ws + o;
    o += (size_t)2 * MR * 2 * DI / 2;
    __hip_bfloat16* xsb2 = (__hip_bfloat16*)(ws + o); o += (size_t)2 * MR * DI / 2;
    // ycat region (4,194,304 floats): x-proj split-K partials [2][KS][MR][XLD]
    // fp32 first (dead after xproj_reduce), then ycat bf16 [MR][2DI] (scan3).
    __hip_bfloat16* ycat = (__hip_bfloat16*)(ws + o);
    float* xpart = ws + o;
    o += (size_t)MR * 2 * DI / 2;
    float* xdb2 = ws + o; o += (size_t)2 * MR * XLD;
    __hip_bfloat16* xdbt = (__hip_bfloat16*)(ws + o); o += (size_t)2 * MR * 64 / 2;
    __hip_bfloat16* dtfb = (__hip_bfloat16*)(ws + o); o += (size_t)2 * MR * DI / 2;
    __hip_bfloat16* nb = (__hip_bfloat16*)(ws + o); o += (size_t)MR * DM / 2;
    // weight arena (bf16), 15,466,496 elements = 7,733,248 floats:
    __hip_bfloat16* warena = (__hip_bfloat16*)(ws + o); o += 15466496 / 2;
    float* hbuf = ws + o;
    size_t base_floats = o;

    __hip_bfloat16* wbi  = warena;               // [2][2DI][DM]    8,388,608
    __hip_bfloat16* pwb  = warena +  8388608;    // [DM][2DM]       2,097,152
    __hip_bfloat16* wdt  = warena + 10485760;    // [2][DI][64]       262,144
    __hip_bfloat16* wpb2 = warena + 10747904;    // [2][128][DI]      524,288
    __hip_bfloat16* wcat = warena + 11272192;    // [DM][2DI]       4,194,304  -> end 15,466,496

    const size_t slab = (size_t)NB * DI * DST;   // 65536
    int G = 32;
    while (G > 4 && (base_floats + 4ull * G * slab) * 4 > ws_size) G >>= 1;
    int useChunks = ((base_floats + 4ull * G * slab) * 4 <= ws_size);
    float* hend  = hbuf;
    float* aprod = hbuf + 2ull * G * slab;
    int Cn = useChunks ? LL / G : LL;

    // weight prep
    cvt_all_k<<<10496, 256, 0, stream>>>(f_inW, b_inW, proj_W, f_dtW, b_dtW, warena);
    cvt_pad96_k<<<dim3(64, 2), 256, 0, stream>>>(f_xprojW, b_xprojW, wpb2);
    transpose_k<<<dim3(DI / 64, DM / 64, 2), 256, 0, stream>>>(f_outW, b_outW, wot);
    // Wcat[e, z*DI+d] = sum_{e'} proj_W[e, z*DM+e'] * outW_z[e', d]
    gemm_gl<1><<<dim3(DI / 128, DM / 128, 2), 256, 0, stream>>>(
        pwb, 2 * DM, (size_t)DM, wot, DM, (size_t)DI * DM,
        wcat, 2 * DI, (size_t)DI, DM, nullptr, nullptr);

    // layernorm
    layernorm_k<<<MR, 256, 0, stream>>>(x, ln_w, ln_b, nb);

    // in-proj both dirs: xz2[dir] = nb @ inW[dir]^T (bf16) — overwrites wot
    gemm_gl<1><<<dim3((2 * DI) / 128, MR / 128, 2), 256, 0, stream>>>(
        nb, DM, 0, wbi, DM, (size_t)2 * DI * DM,
        xz2, 2 * DI, (size_t)MR * 2 * DI, DM, nullptr, nullptr);

    // conv + silu both dirs -> xsb2
    conv_silu_k<<<dim3((MR * DI) / 256, 2), 256, 0, stream>>>(
        xz2, f_convW, f_convb, b_convW, b_convb, xsb2);

    // x-proj split-K + reduce -> xdb2 fp32 (+ dt cols bf16); partials in ycat region
    xproj_part_k<<<dim3(KS, MR / 128, 2), 256, 0, stream>>>(xsb2, wpb2, xpart);
    xproj_reduce_k<<<dim3((MR * XLD) / 1024, 2), 256, 0, stream>>>(xpart, xdb2, xdbt);

    // dt-proj both dirs via MFMA: dtfb = softplus(xdbt @ dtW^T + dtb) (bf16)
    gemm_gl<3><<<dim3(DI / 128, MR / 128, 2), 256, 0, stream>>>(
        xdbt, 64, (size_t)MR * 64, wdt, 64, (size_t)DI * 64,
        dtfb, DI, (size_t)MR * DI, 64, f_dtb, b_dtb);

    // selective scan both dirs -> ycat [MR][2*DI]
    if (useChunks) {
        scan1_k<<<dim3(DI / 256, NB, 2 * G), 256, 0, stream>>>(
            dtfb, xsb2, xdb2, f_A_log, b_A_log, hend, aprod, G, Cn);
        scan2_k<<<dim3((NB * DI * DST) / 256, 2), 256, 0, stream>>>(hend, aprod, G);
        scan3_k<<<dim3(DI / 256, NB, 2 * G), 256, 0, stream>>>(
            dtfb, xsb2, xdb2, xz2, f_A_log, b_A_log, f_Dskip, b_Dskip,
            hend, ycat, G, Cn);
    } else {
        scan_mono_k<<<dim3(DI / 256, NB, 2), 256, 0, stream>>>(
            dtfb, xsb2, xdb2, xz2, f_A_log, b_A_log, f_Dskip, b_Dskip, ycat);
    }

    // final GEMM split-K over K=4096: fpart[z] = ycat[:, z*1024:+1024] @ Wcat_z^T
    // (overwrites xz2 region — dead after scan3)
    gemm_gl<0><<<dim3(DM / 128, MR / 128, 4), 256, 0, stream>>>(
        ycat, 2 * DI, 1024, wcat, 2 * DI, 1024,
        fpart, DM, (size_t)MR * DM, 1024, nullptr, nullptr);

    // out = x + proj_b + sum_z fpart
    final_reduce_k<<<(MR * DM) / 1024, 256, 0, stream>>>(
        fpart, x, proj_b, (float*)d_out);
}